// Round 7
// baseline (397.396 us; speedup 1.0000x reference)
//
#include <hip/hip_runtime.h>

// KNN (K=8) + inverse-distance-weighted average, MFMA screening version.
// data1: [N=4096, D=1024] fp32, data2: [M=8192, D=1024] fp32, out: [N, D] fp32.
//
// (Resubmission of R6 kernel — R6 bench failed with an infra error
// "MI355X container failed twice"; no measurement was taken. Source is
// unchanged so the R5->R6 delta stays attributable.)
//
// Fast path:
//  1) convert_all: A -> bf16; B -> bf16 fused with y2[m]=||B[m]||^2
//  2) screen10: bf16 16x16x32 MFMA GEMM (R5 lesson: 32x32 fragment reads
//     [row=lane&31, 1 chunk/half-wave] are intrinsically 4-8-way bank
//     conflicted with any 64B-row XOR swizzle -> 1.05e7 conflicts, 236us.
//     The 16x16 pattern [16 rows x 4 chunks/wave] is verified 0-conflict).
//     Economy fix vs screen8 (LDS-issue bound: 4.7M ds_reads = 92us): wave
//     tile 32x128, acc[2][8] -> 10 ds_read per 16 MFMA (0.625 ds/MFMA, was
//     1.125). Block 128x128, 4 waves, ring-3 LDS 48KB -> 3 blocks/CU, 12
//     waves/CU. K-loop unrolled x3 -> compile-time ring slots -> ds_read
//     immediate offsets, no per-slice addr VALU. Counted vmcnt(4), setprio,
//     XCD swizzle (XCD owns 8 windows -> 2 MB B L2-resident). Candidate
//     layout identical to screen5..9 (64 sorted groups of 8 per row).
//  3) finalize6: 2 waves per row; 512 sorted-8 groups -> 6-level butterfly
//     bitonic keep-12 merge -> EXACT fp32 rescore with B fragments RETAINED
//     in registers -> top-8 by (d2, idx) -> w = 1/(sqrt(max(d2,1e-12))+0.1)
//     -> weighted sum from registers.
// Fallback (small ws): round-1 pure-fp32 path (verified correct).

typedef short bf16x8 __attribute__((ext_vector_type(8)));
typedef float f32x4 __attribute__((ext_vector_type(4)));

#define SENTINEL 1e30f
#define BKK 32

static __device__ __forceinline__ unsigned short f2bf(float f) {
  unsigned u = __float_as_uint(f);
  return (unsigned short)((u + 0x7fffu + ((u >> 16) & 1u)) >> 16);
}

// ---------------- fast path kernels ----------------
// grid: N + M blocks. bid < N: convert A row. else: convert B row + norm.
__global__ __launch_bounds__(256) void convert_all_kernel(
    const float* __restrict__ A, const float* __restrict__ B,
    unsigned short* __restrict__ Abf, unsigned short* __restrict__ Bbf,
    float* __restrict__ y2, int N) {
  const int bid = blockIdx.x;
  const int tid = threadIdx.x;
  if (bid < N) {
    const float4 v = ((const float4*)&A[(size_t)bid * 1024])[tid];
    ushort4 o;
    o.x = f2bf(v.x); o.y = f2bf(v.y); o.z = f2bf(v.z); o.w = f2bf(v.w);
    ((ushort4*)&Abf[(size_t)bid * 1024])[tid] = o;
  } else {
    const int m = bid - N;
    __shared__ float red[256];
    const float4 v = ((const float4*)&B[(size_t)m * 1024])[tid];
    ushort4 o;
    o.x = f2bf(v.x); o.y = f2bf(v.y); o.z = f2bf(v.z); o.w = f2bf(v.w);
    ((ushort4*)&Bbf[(size_t)m * 1024])[tid] = o;
    red[tid] = v.x * v.x + v.y * v.y + v.z * v.z + v.w * v.w;
    __syncthreads();
    for (int s = 128; s > 0; s >>= 1) {
      if (tid < s) red[tid] += red[tid + s];
      __syncthreads();
    }
    if (tid == 0) y2[m] = red[0];
  }
}

// ascending compare-exchange on (s, i) register pairs
#define CAS(sa, ia, sb, ib)                         \
  do {                                              \
    if ((sa) > (sb)) {                              \
      const float _t = (sa); (sa) = (sb); (sb) = _t;\
      const int _u = (ia); (ia) = (ib); (ib) = _u;  \
    }                                               \
  } while (0)

// stage k-slice sk (k0 = sk*32) into LDS ring slot b (compile-time b).
// Wave w stages A rows [w*32,w*32+32) and B rows [w*32,w*32+32): 4 glds.
#define STAGE(sk, b)                                                          \
  do {                                                                        \
    const unsigned short* gA_ =                                               \
        Abf + (size_t)(r0 + w * 32 + srow) * 1024 + (sk) * 32 + sofs;         \
    const unsigned short* gB_ =                                               \
        Bbf + (size_t)(c0 + w * 32 + srow) * 1024 + (sk) * 32 + sofs;         \
    __builtin_amdgcn_global_load_lds(                                         \
        (const __attribute__((address_space(1))) void*)gA_,                   \
        (__attribute__((address_space(3))) void*)&As[b][(w * 32) * 32],       \
        16, 0, 0);                                                            \
    __builtin_amdgcn_global_load_lds(                                         \
        (const __attribute__((address_space(1))) void*)(gA_ + (size_t)16 * 1024), \
        (__attribute__((address_space(3))) void*)&As[b][(w * 32 + 16) * 32],  \
        16, 0, 0);                                                            \
    __builtin_amdgcn_global_load_lds(                                         \
        (const __attribute__((address_space(1))) void*)gB_,                   \
        (__attribute__((address_space(3))) void*)&Bs[b][(w * 32) * 32],       \
        16, 0, 0);                                                            \
    __builtin_amdgcn_global_load_lds(                                         \
        (const __attribute__((address_space(1))) void*)(gB_ + (size_t)16 * 1024), \
        (__attribute__((address_space(3))) void*)&Bs[b][(w * 32 + 16) * 32],  \
        16, 0, 0);                                                            \
  } while (0)

// 10 ds_read_b128 (compile-time slot -> immediate offsets) feed 16 MFMA16.
#define COMPUTE(b)                                                            \
  do {                                                                        \
    bf16x8 af[2], bfr[8];                                                     \
    _Pragma("unroll")                                                         \
    for (int fi = 0; fi < 2; ++fi)                                            \
      af[fi] = *(const bf16x8*)&As[b][(frowA + fi * 16) * 32 + fofs];         \
    _Pragma("unroll")                                                         \
    for (int fj = 0; fj < 8; ++fj)                                            \
      bfr[fj] = *(const bf16x8*)&Bs[b][(frowB + fj * 16) * 32 + fofs];        \
    __builtin_amdgcn_s_setprio(1);                                            \
    _Pragma("unroll")                                                         \
    for (int fi = 0; fi < 2; ++fi)                                            \
      _Pragma("unroll")                                                       \
      for (int fj = 0; fj < 8; ++fj)                                          \
        acc[fi][fj] = __builtin_amdgcn_mfma_f32_16x16x32_bf16(                \
            bfr[fj], af[fi], acc[fi][fj], 0, 0, 0);                           \
    __builtin_amdgcn_s_setprio(0);                                            \
  } while (0)

// counted-vmcnt sync: slice t complete for this wave, then block barrier.
#define PIPE_SYNC(N)                                                          \
  do {                                                                        \
    asm volatile("s_waitcnt vmcnt(" #N ")" ::: "memory");                     \
    __builtin_amdgcn_sched_barrier(0);                                        \
    __builtin_amdgcn_s_barrier();                                             \
    __builtin_amdgcn_sched_barrier(0);                                        \
  } while (0)

// grid: (64, 32) = 2048 blocks x 256 threads (3 blocks/CU, 12 waves/CU).
// blockIdx.x -> xcd = bx&7; window = xcd*8 + ((bx>>3)&7) [XCD owns 8
// windows = 1024 B-cols = 2 MB L2-resident]; rowtile = blockIdx.y.
// Block tile 128 rows x 128 cols; wave w owns rows [w*32, w*32+32) via
// 2 fi x 8 fj 16x16 MFMA tiles. K-loop: ring-3 LDS slices (BK=32),
// unrolled x3 (compile-time slots), vmcnt(4)/barrier per slice, prefetch
// distance 2.
__global__ __launch_bounds__(256) void screen10_kernel(
    const unsigned short* __restrict__ Abf, const unsigned short* __restrict__ Bbf,
    const float* __restrict__ y2g,
    float* __restrict__ cand_s, int* __restrict__ cand_i) {
  __shared__ unsigned short As[3][128 * 32];  // 24 KB
  __shared__ unsigned short Bs[3][128 * 32];  // 24 KB

  const int tid = threadIdx.x;
  const int w = tid >> 6;        // 0..3
  const int lane = tid & 63;

  const int bx = blockIdx.x;                        // 0..63
  const int window = (bx & 7) * 8 + ((bx >> 3) & 7);  // 0..63
  const int r0 = blockIdx.y * 128;
  const int c0 = window * 128;

  // staging: lane -> LDS slot (16 rows per glds), swizzle on global source
  const int srow = lane >> 2;                          // 0..15
  const int sofs = ((lane & 3) ^ ((lane >> 3) & 3)) * 8;

  // fragment reads: LDS col = kc ^ ((row>>1)&3), kc = lane>>4 (verified
  // 0-conflict pattern from screen6/8)
  const int frowA = w * 32 + (lane & 15);
  const int frowB = lane & 15;
  const int fofs = ((lane >> 4) ^ ((lane >> 1) & 3)) * 8;
  const int cgrp = (lane >> 4) * 4;

  f32x4 acc[2][8];
#pragma unroll
  for (int fi = 0; fi < 2; ++fi)
#pragma unroll
    for (int fj = 0; fj < 8; ++fj) {
      f32x4 z = {0.f, 0.f, 0.f, 0.f};
      acc[fi][fj] = z;
    }

  // prologue: 2 slices in flight (8 outstanding glds per wave)
  STAGE(0, 0);
  STAGE(1, 1);
  // main loop: 30 slices in 10 unrolled triples; slice s lives in slot s%3
  int t = 0;
#pragma unroll 1
  for (int it = 0; it < 10; ++it) {
    PIPE_SYNC(4);          // slice t staged; t+1 in flight
    STAGE(t + 2, 2);
    __builtin_amdgcn_sched_barrier(0);
    COMPUTE(0);            // slice t (t%3==0)
    PIPE_SYNC(4);
    STAGE(t + 3, 0);
    __builtin_amdgcn_sched_barrier(0);
    COMPUTE(1);            // slice t+1
    PIPE_SYNC(4);
    STAGE(t + 4, 1);
    __builtin_amdgcn_sched_barrier(0);
    COMPUTE(2);            // slice t+2
    t += 3;
  }
  // t == 30: slices 30 (slot 0) and 31 (slot 1) remain; 31 still in flight
  PIPE_SYNC(4);
  COMPUTE(0);              // slice 30
  PIPE_SYNC(0);
  COMPUTE(1);              // slice 31

  // barrier-free epilogue. Lane's cands: row = r0 + w*32 + fi*16 + (lane&15),
  // col = c0 + fj*16 + cgrp + reg. y2 read directly from global (L2-hot).
#pragma unroll
  for (int fi = 0; fi < 2; ++fi) {
    float ls[8];
    int li[8];
#pragma unroll
    for (int j = 0; j < 8; ++j) { ls[j] = SENTINEL; li[j] = 0x7fffffff; }
    const int cb = c0 + cgrp;
#pragma unroll
    for (int fj = 0; fj < 8; ++fj) {
      const float4 y2q = *(const float4*)&y2g[c0 + fj * 16 + cgrp];
#pragma unroll
      for (int reg = 0; reg < 4; ++reg) {
        const float s = y2q[reg] - 2.0f * acc[fi][fj][reg];
        if (s < ls[7]) {
          ls[7] = s; li[7] = cb + fj * 16 + reg;
#pragma unroll
          for (int j = 7; j > 0; --j) {
            if (ls[j] < ls[j - 1]) {
              const float tt = ls[j]; ls[j] = ls[j - 1]; ls[j - 1] = tt;
              const int u2 = li[j]; li[j] = li[j - 1]; li[j - 1] = u2;
            }
          }
        }
      }
    }
    // merge sorted 8-lists across the 4 lanes sharing this row
#pragma unroll
    for (int off = 16; off <= 32; off <<= 1) {
      float rs[8];
      int ri[8];
#pragma unroll
      for (int j = 0; j < 8; ++j) {
        rs[j] = __shfl_xor(ls[j], off, 64);
        ri[j] = __shfl_xor(li[j], off, 64);
      }
      float ms[8];
      int mi_[8];
#pragma unroll
      for (int i = 0; i < 8; ++i) {
        const bool tk = ls[i] < rs[7 - i];
        ms[i] = tk ? ls[i] : rs[7 - i];
        mi_[i] = tk ? li[i] : ri[7 - i];
      }
      CAS(ms[0], mi_[0], ms[4], mi_[4]);
      CAS(ms[1], mi_[1], ms[5], mi_[5]);
      CAS(ms[2], mi_[2], ms[6], mi_[6]);
      CAS(ms[3], mi_[3], ms[7], mi_[7]);
      CAS(ms[0], mi_[0], ms[2], mi_[2]);
      CAS(ms[1], mi_[1], ms[3], mi_[3]);
      CAS(ms[4], mi_[4], ms[6], mi_[6]);
      CAS(ms[5], mi_[5], ms[7], mi_[7]);
      CAS(ms[0], mi_[0], ms[1], mi_[1]);
      CAS(ms[2], mi_[2], ms[3], mi_[3]);
      CAS(ms[4], mi_[4], ms[5], mi_[5]);
      CAS(ms[6], mi_[6], ms[7], mi_[7]);
#pragma unroll
      for (int j = 0; j < 8; ++j) { ls[j] = ms[j]; li[j] = mi_[j]; }
    }
    if ((lane >> 4) == 0) {  // lanes 0..15 hold the merged per-row top-8
      const int row = r0 + w * 32 + fi * 16 + lane;
      const size_t base = ((size_t)row * 64 + window) * 8;
#pragma unroll
      for (int j = 0; j < 8; ++j) {
        cand_s[base + j] = ls[j];
        cand_i[base + j] = li[j];
      }
    }
  }
}

// 2 waves per row: grid N/2 blocks x 256 threads (4 waves = 2 rows x 2
// wave-halves). Lane loads sorted group `lane` (8 contiguous cands) ->
// 6-level butterfly bitonic keep-12 merge -> exact fp32 rescore with B
// fragments kept in registers -> top-8 -> weighted sum from registers.
__global__ __launch_bounds__(256) void finalize6_kernel(
    const float* __restrict__ A, const float* __restrict__ B,
    const float* __restrict__ y2g,
    const float* __restrict__ cand_s, const int* __restrict__ cand_i,
    float* __restrict__ out) {
  const int tid = threadIdx.x;
  const int w = tid >> 6;
  const int lane = tid & 63;
  const int rloc = w >> 1;  // row within block
  const int wh = w & 1;     // wave-half along D
  const int n = blockIdx.x * 2 + rloc;
  __shared__ float comb[2][2][16];

  float s12[12];
  int i12[12];
  {
    const float4* cs = (const float4*)&cand_s[(size_t)n * 512 + lane * 8];
    const int4* cj = (const int4*)&cand_i[(size_t)n * 512 + lane * 8];
    const float4 sa = cs[0], sb = cs[1];
    const int4 ja = cj[0], jb = cj[1];
    s12[0] = sa.x; s12[1] = sa.y; s12[2] = sa.z; s12[3] = sa.w;
    s12[4] = sb.x; s12[5] = sb.y; s12[6] = sb.z; s12[7] = sb.w;
    i12[0] = ja.x; i12[1] = ja.y; i12[2] = ja.z; i12[3] = ja.w;
    i12[4] = jb.x; i12[5] = jb.y; i12[6] = jb.z; i12[7] = jb.w;
#pragma unroll
    for (int j = 8; j < 12; ++j) { s12[j] = SENTINEL; i12[j] = 0x7fffffff; }
  }

  // butterfly merge: sorted-12 + sorted-12 -> lowest-12 sorted.
#pragma unroll
  for (int off = 1; off <= 32; off <<= 1) {
    float rs[12];
    int ri[12];
#pragma unroll
    for (int j = 0; j < 12; ++j) {
      rs[j] = __shfl_xor(s12[j], off, 64);
      ri[j] = __shfl_xor(i12[j], off, 64);
    }
    float ms[12];
    int mj[12];
#pragma unroll
    for (int j = 0; j < 12; ++j) {
      const bool tke = s12[j] < rs[11 - j];
      ms[j] = tke ? s12[j] : rs[11 - j];
      mj[j] = tke ? i12[j] : ri[11 - j];
    }
    CAS(ms[0], mj[0], ms[8], mj[8]);  CAS(ms[1], mj[1], ms[9], mj[9]);
    CAS(ms[2], mj[2], ms[10], mj[10]); CAS(ms[3], mj[3], ms[11], mj[11]);
    CAS(ms[4], mj[4], ms[8], mj[8]);  CAS(ms[5], mj[5], ms[9], mj[9]);
    CAS(ms[6], mj[6], ms[10], mj[10]); CAS(ms[7], mj[7], ms[11], mj[11]);
    CAS(ms[0], mj[0], ms[2], mj[2]);  CAS(ms[1], mj[1], ms[3], mj[3]);
    CAS(ms[4], mj[4], ms[6], mj[6]);  CAS(ms[5], mj[5], ms[7], mj[7]);
    CAS(ms[8], mj[8], ms[10], mj[10]); CAS(ms[9], mj[9], ms[11], mj[11]);
    CAS(ms[0], mj[0], ms[1], mj[1]);  CAS(ms[2], mj[2], ms[3], mj[3]);
    CAS(ms[4], mj[4], ms[5], mj[5]);  CAS(ms[6], mj[6], ms[7], mj[7]);
    CAS(ms[8], mj[8], ms[9], mj[9]);  CAS(ms[10], mj[10], ms[11], mj[11]);
#pragma unroll
    for (int j = 0; j < 12; ++j) { s12[j] = ms[j]; i12[j] = mj[j]; }
  }
  // i12[0..11]: approx top-12 indices, identical in every lane/wave.

  // exact fp32 partial dots; B fragments RETAINED for the output sum.
  const float4* Arow = (const float4*)&A[(size_t)n * 1024];
  const int fbase = wh * 128 + lane * 2;
  float4 a4[2];
  a4[0] = Arow[fbase];
  a4[1] = Arow[fbase + 1];
  float4 bk0[12], bk1[12];
#pragma unroll
  for (int j = 0; j < 12; ++j) {
    const float4* Brow = (const float4*)&B[(size_t)i12[j] * 1024];
    bk0[j] = Brow[fbase];
    bk1[j] = Brow[fbase + 1];
  }
  float part[13];
  part[12] = a4[0].x * a4[0].x + a4[0].y * a4[0].y + a4[0].z * a4[0].z +
             a4[0].w * a4[0].w + a4[1].x * a4[1].x + a4[1].y * a4[1].y +
             a4[1].z * a4[1].z + a4[1].w * a4[1].w;
#pragma unroll
  for (int j = 0; j < 12; ++j) {
    part[j] = a4[0].x * bk0[j].x + a4[0].y * bk0[j].y + a4[0].z * bk0[j].z +
              a4[0].w * bk0[j].w;
    part[j] += a4[1].x * bk1[j].x + a4[1].y * bk1[j].y + a4[1].z * bk1[j].z +
               a4[1].w * bk1[j].w;
  }
#pragma unroll
  for (int r = 0; r < 13; ++r) {
#pragma unroll
    for (int off = 32; off >= 1; off >>= 1) part[r] += __shfl_xor(part[r], off, 64);
  }
  if (lane == 0) {
#pragma unroll
    for (int r = 0; r < 13; ++r) comb[rloc][wh][r] = part[r];
  }
  __syncthreads();
  float tot[13];
#pragma unroll
  for (int r = 0; r < 13; ++r) tot[r] = comb[rloc][0][r] + comb[rloc][1][r];

  // uniform redundant selection: top-8 by (d2, idx); weights land in wsel[]
  const float x2 = tot[12];
  float d2v[12];
  float wsel[12];
  bool used[12];
#pragma unroll
  for (int j = 0; j < 12; ++j) {
    d2v[j] = x2 + y2g[i12[j]] - 2.0f * tot[j];
    used[j] = false;
    wsel[j] = 0.0f;
  }
  float wsum = 0.0f;
  for (int k = 0; k < 8; ++k) {
    float bd = SENTINEL;
    int bi = 0x7fffffff, bslot = 0;
#pragma unroll
    for (int j = 0; j < 12; ++j) {
      if (used[j]) continue;
      const float d2 = d2v[j];
      if (d2 < bd || (d2 == bd && i12[j] < bi)) { bd = d2; bi = i12[j]; bslot = j; }
    }
    used[bslot] = true;
    const float d2c = fmaxf(bd, 1e-12f);
    const float wv = 1.0f / (sqrtf(d2c) + 0.1f);
    wsel[bslot] = wv;
    wsum += wv;
  }
  const float inv = 1.0f / wsum;

  float4 o0 = {0, 0, 0, 0}, o1 = {0, 0, 0, 0};
#pragma unroll
  for (int j = 0; j < 12; ++j) {
    const float wv = wsel[j];
    o0.x += wv * bk0[j].x; o0.y += wv * bk0[j].y;
    o0.z += wv * bk0[j].z; o0.w += wv * bk0[j].w;
    o1.x += wv * bk1[j].x; o1.y += wv * bk1[j].y;
    o1.z += wv * bk1[j].z; o1.w += wv * bk1[j].w;
  }
  o0.x *= inv; o0.y *= inv; o0.z *= inv; o0.w *= inv;
  o1.x *= inv; o1.y *= inv; o1.z *= inv; o1.w *= inv;
  float4* Orow = (float4*)&out[(size_t)n * 1024];
  Orow[fbase] = o0;
  Orow[fbase + 1] = o1;
}

// ---------------- fallback path (round-1, verified) ----------------
__global__ __launch_bounds__(256) void rownorm_kernel(
    const float* __restrict__ B, float* __restrict__ y2) {
  const int m = blockIdx.x;
  const int tid = threadIdx.x;
  __shared__ float red[256];
  const float4 v = *(const float4*)&B[(size_t)m * 1024 + tid * 4];
  red[tid] = v.x * v.x + v.y * v.y + v.z * v.z + v.w * v.w;
  __syncthreads();
  for (int s = 128; s > 0; s >>= 1) {
    if (tid < s) red[tid] += red[tid + s];
    __syncthreads();
  }
  if (tid == 0) y2[m] = red[0];
}

__global__ __launch_bounds__(256) void knn_chunk_kernel(
    const float* __restrict__ A, const float* __restrict__ B,
    const float* __restrict__ y2g,
    float* __restrict__ cand_s, int* __restrict__ cand_i) {
  __shared__ float As[BKK][68];
  __shared__ float Bs[BKK][68];
  __shared__ float Sc[64][65];

  const int tid = threadIdx.x;
  const int tx = tid & 15;
  const int ty = tid >> 4;
  const int r0 = blockIdx.y * 64;
  const int c0 = blockIdx.x * 1024;
  const int lrow = tid >> 3;
  const int lk = (tid & 7) * 4;

  float top_s[8];
  int top_i[8];
#pragma unroll
  for (int j = 0; j < 8; ++j) { top_s[j] = SENTINEL; top_i[j] = 0x7fffffff; }

  for (int tile = 0; tile < 16; ++tile) {
    const int cbase = c0 + tile * 64;
    float acc[4][4];
#pragma unroll
    for (int i = 0; i < 4; ++i)
#pragma unroll
      for (int j = 0; j < 4; ++j) acc[i][j] = 0.0f;

    for (int k0 = 0; k0 < 1024; k0 += BKK) {
      const float4 a0 = *(const float4*)&A[(size_t)(r0 + lrow) * 1024 + k0 + lk];
      const float4 a1 = *(const float4*)&A[(size_t)(r0 + lrow + 32) * 1024 + k0 + lk];
      const float4 b0 = *(const float4*)&B[(size_t)(cbase + lrow) * 1024 + k0 + lk];
      const float4 b1 = *(const float4*)&B[(size_t)(cbase + lrow + 32) * 1024 + k0 + lk];
      __syncthreads();
      As[lk + 0][lrow] = a0.x; As[lk + 1][lrow] = a0.y;
      As[lk + 2][lrow] = a0.z; As[lk + 3][lrow] = a0.w;
      As[lk + 0][lrow + 32] = a1.x; As[lk + 1][lrow + 32] = a1.y;
      As[lk + 2][lrow + 32] = a1.z; As[lk + 3][lrow + 32] = a1.w;
      Bs[lk + 0][lrow] = b0.x; Bs[lk + 1][lrow] = b0.y;
      Bs[lk + 2][lrow] = b0.z; Bs[lk + 3][lrow] = b0.w;
      Bs[lk + 0][lrow + 32] = b1.x; Bs[lk + 1][lrow + 32] = b1.y;
      Bs[lk + 2][lrow + 32] = b1.z; Bs[lk + 3][lrow + 32] = b1.w;
      __syncthreads();
#pragma unroll
      for (int kk = 0; kk < BKK; ++kk) {
        const float4 av = *(const float4*)&As[kk][ty * 4];
        const float4 bv = *(const float4*)&Bs[kk][tx * 4];
        acc[0][0] += av.x * bv.x; acc[0][1] += av.x * bv.y;
        acc[0][2] += av.x * bv.z; acc[0][3] += av.x * bv.w;
        acc[1][0] += av.y * bv.x; acc[1][1] += av.y * bv.y;
        acc[1][2] += av.y * bv.z; acc[1][3] += av.y * bv.w;
        acc[2][0] += av.z * bv.x; acc[2][1] += av.z * bv.y;
        acc[2][2] += av.z * bv.z; acc[2][3] += av.z * bv.w;
        acc[3][0] += av.w * bv.x; acc[3][1] += av.w * bv.y;
        acc[3][2] += av.w * bv.z; acc[3][3] += av.w * bv.w;
      }
    }
#pragma unroll
    for (int i = 0; i < 4; ++i) {
      const int row = ty * 4 + i;
#pragma unroll
      for (int j = 0; j < 4; ++j) {
        const int col = tx * 4 + j;
        Sc[row][col] = y2g[cbase + col] - 2.0f * acc[i][j];
      }
    }
    __syncthreads();
    if (tid < 64) {
      for (int c = 0; c < 64; ++c) {
        const float s = Sc[tid][c];
        if (s < top_s[7]) {
          top_s[7] = s; top_i[7] = cbase + c;
#pragma unroll
          for (int j = 7; j > 0; --j) {
            if (top_s[j] < top_s[j - 1]) {
              const float tss = top_s[j]; top_s[j] = top_s[j - 1]; top_s[j - 1] = tss;
              const int tii = top_i[j]; top_i[j] = top_i[j - 1]; top_i[j - 1] = tii;
            }
          }
        }
      }
    }
  }

  if (tid < 64) {
    const int n = r0 + tid;
    const int base = (n * gridDim.x + blockIdx.x) * 8;
#pragma unroll
    for (int j = 0; j < 8; ++j) {
      cand_s[base + j] = top_s[j];
      cand_i[base + j] = top_i[j];
    }
  }
}

__global__ __launch_bounds__(256) void finalize_kernel(
    const float* __restrict__ A, const float* __restrict__ B,
    const float* __restrict__ cand_s, const int* __restrict__ cand_i,
    float* __restrict__ out, int nchunks) {
  const int n = blockIdx.x;
  const int tid = threadIdx.x;
  __shared__ float red[256];
  __shared__ float ls[64];
  __shared__ int li[64];
  __shared__ float wsh2[8];
  __shared__ int wid[8];
  __shared__ float wsum_sh;

  const int ncand = nchunks * 8;
  const float4 a = *(const float4*)&A[(size_t)n * 1024 + tid * 4];
  red[tid] = a.x * a.x + a.y * a.y + a.z * a.z + a.w * a.w;
  if (tid < ncand) {
    ls[tid] = cand_s[n * ncand + tid];
    li[tid] = cand_i[n * ncand + tid];
  }
  __syncthreads();
  for (int s = 128; s > 0; s >>= 1) {
    if (tid < s) red[tid] += red[tid + s];
    __syncthreads();
  }
  if (tid == 0) {
    const float x2 = red[0];
    float wsum = 0.0f;
    for (int j = 0; j < 8; ++j) {
      float bs = SENTINEL;
      int bi = 0x7fffffff;
      int bp = 0;
      for (int c = 0; c < ncand; ++c) {
        const float s_ = ls[c];
        const int i_ = li[c];
        if (s_ < bs || (s_ == bs && i_ < bi)) { bs = s_; bi = i_; bp = c; }
      }
      ls[bp] = SENTINEL; li[bp] = 0x7fffffff;
      float d2 = x2 + bs;
      d2 = fmaxf(d2, 1e-12f);
      const float wkk = 1.0f / (sqrtf(d2) + 0.1f);
      wsh2[j] = wkk; wid[j] = bi;
      wsum += wkk;
    }
    wsum_sh = wsum;
  }
  __syncthreads();
  const float inv = 1.0f / wsum_sh;
  float ox = 0.0f, oy = 0.0f, oz = 0.0f, ow = 0.0f;
#pragma unroll
  for (int j = 0; j < 8; ++j) {
    const float wkk = wsh2[j];
    const float4 v = *(const float4*)&B[(size_t)wid[j] * 1024 + tid * 4];
    ox += wkk * v.x; oy += wkk * v.y; oz += wkk * v.z; ow += wkk * v.w;
  }
  float4 o;
  o.x = ox * inv; o.y = oy * inv; o.z = oz * inv; o.w = ow * inv;
  *(float4*)&out[(size_t)n * 1024 + tid * 4] = o;
}

extern "C" void kernel_launch(void* const* d_in, const int* in_sizes, int n_in,
                              void* d_out, int out_size, void* d_ws, size_t ws_size,
                              hipStream_t stream) {
  const float* A = (const float*)d_in[0];
  const float* Bm = (const float*)d_in[1];
  const int D = 1024;
  const int N = in_sizes[0] / D;  // 4096
  const int M = in_sizes[1] / D;  // 8192

  const size_t needA = (size_t)N * D * 2;
  const size_t needB = (size_t)M * D * 2;
  const size_t needC = (size_t)N * 512 * 4;  // cand_s (== cand_i)
  const size_t need = needA + needB + (size_t)M * 4 + 2 * needC;

  if (ws_size >= need && M == 8192 && N % 128 == 0 && N % 2 == 0) {
    unsigned short* Abf = (unsigned short*)d_ws;
    unsigned short* Bbf = Abf + (size_t)N * D;
    float* y2 = (float*)(Bbf + (size_t)M * D);
    float* cand_s = y2 + M;
    int* cand_i = (int*)(cand_s + (size_t)N * 512);

    convert_all_kernel<<<N + M, 256, 0, stream>>>(A, Bm, Abf, Bbf, y2, N);
    dim3 g(64, N / 128);
    screen10_kernel<<<g, 256, 0, stream>>>(Abf, Bbf, y2, cand_s, cand_i);
    finalize6_kernel<<<N / 2, 256, 0, stream>>>(A, Bm, y2, cand_s, cand_i,
                                                (float*)d_out);
  } else {
    float* y2 = (float*)d_ws;
    float* cand_s = y2 + M;
    int* cand_i = (int*)(cand_s + (size_t)N * 64);
    rownorm_kernel<<<M, 256, 0, stream>>>(Bm, y2);
    dim3 gridB(M / 1024, N / 64);
    knn_chunk_kernel<<<gridB, 256, 0, stream>>>(A, Bm, y2, cand_s, cand_i);
    finalize_kernel<<<N, 256, 0, stream>>>(A, Bm, cand_s, cand_i, (float*)d_out, M / 1024);
  }
}

// Round 8
// 349.905 us; speedup vs baseline: 1.1357x; 1.1357x over previous
//
#include <hip/hip_runtime.h>

// KNN (K=8) + inverse-distance-weighted average, MFMA screening version.
// data1: [N=4096, D=1024] fp32, data2: [M=8192, D=1024] fp32, out: [N, D] fp32.
//
// Fast path:
//  1) convert_all: A -> bf16; B -> bf16 fused with y2[m]=||B[m]||^2
//  2) screen11: bf16 16x16x32 MFMA GEMM, m97-style PLAIN sync structure.
//     R7 lesson: the ring-3 + counted-vmcnt + sched_barrier(0) scaffolding
//     was the poison (272us; m141 analog: sched walls defeat the compiler
//     scheduler). This kernel keeps screen10's verified geometry (128x128
//     block, 4 waves, wave tile 32x128, acc[2][8], 0-conflict swizzles,
//     identical candidate layout) but uses the measured-874TF m97 loop:
//     single 16KB LDS buffer, {syncthreads; STAGE(glds x16B); syncthreads;
//     COMPUTE} per BK=32 slice, compiler-managed waitcnts. LDS 48->16KB ->
//     ~4 blocks/CU (VGPR-limited), 16 waves/CU: implicit wave-overlap does
//     the pipelining (m114). XCD swizzle: XCD owns 8 windows -> 2 MB B
//     L2-resident.
//  3) finalize6: 2 waves per row; 512 sorted-8 groups -> 6-level butterfly
//     bitonic keep-12 merge -> EXACT fp32 rescore with B fragments RETAINED
//     in registers -> top-8 by (d2, idx) -> w = 1/(sqrt(max(d2,1e-12))+0.1)
//     -> weighted sum from registers.
// Fallback (small ws): round-1 pure-fp32 path (verified correct).

typedef short bf16x8 __attribute__((ext_vector_type(8)));
typedef float f32x4 __attribute__((ext_vector_type(4)));

#define SENTINEL 1e30f
#define BKK 32

static __device__ __forceinline__ unsigned short f2bf(float f) {
  unsigned u = __float_as_uint(f);
  return (unsigned short)((u + 0x7fffu + ((u >> 16) & 1u)) >> 16);
}

// ---------------- fast path kernels ----------------
// grid: N + M blocks. bid < N: convert A row. else: convert B row + norm.
__global__ __launch_bounds__(256) void convert_all_kernel(
    const float* __restrict__ A, const float* __restrict__ B,
    unsigned short* __restrict__ Abf, unsigned short* __restrict__ Bbf,
    float* __restrict__ y2, int N) {
  const int bid = blockIdx.x;
  const int tid = threadIdx.x;
  if (bid < N) {
    const float4 v = ((const float4*)&A[(size_t)bid * 1024])[tid];
    ushort4 o;
    o.x = f2bf(v.x); o.y = f2bf(v.y); o.z = f2bf(v.z); o.w = f2bf(v.w);
    ((ushort4*)&Abf[(size_t)bid * 1024])[tid] = o;
  } else {
    const int m = bid - N;
    __shared__ float red[256];
    const float4 v = ((const float4*)&B[(size_t)m * 1024])[tid];
    ushort4 o;
    o.x = f2bf(v.x); o.y = f2bf(v.y); o.z = f2bf(v.z); o.w = f2bf(v.w);
    ((ushort4*)&Bbf[(size_t)m * 1024])[tid] = o;
    red[tid] = v.x * v.x + v.y * v.y + v.z * v.z + v.w * v.w;
    __syncthreads();
    for (int s = 128; s > 0; s >>= 1) {
      if (tid < s) red[tid] += red[tid + s];
      __syncthreads();
    }
    if (tid == 0) y2[m] = red[0];
  }
}

// ascending compare-exchange on (s, i) register pairs
#define CAS(sa, ia, sb, ib)                         \
  do {                                              \
    if ((sa) > (sb)) {                              \
      const float _t = (sa); (sa) = (sb); (sb) = _t;\
      const int _u = (ia); (ia) = (ib); (ib) = _u;  \
    }                                               \
  } while (0)

// stage k-slice sk (k0 = sk*32) into the single LDS buffer.
// Wave w stages A rows [w*32,w*32+32) and B rows [w*32,w*32+32): 4 glds.
#define STAGE(sk)                                                             \
  do {                                                                        \
    const unsigned short* gA_ =                                               \
        Abf + (size_t)(r0 + w * 32 + srow) * 1024 + (sk) * 32 + sofs;         \
    const unsigned short* gB_ =                                               \
        Bbf + (size_t)(c0 + w * 32 + srow) * 1024 + (sk) * 32 + sofs;         \
    __builtin_amdgcn_global_load_lds(                                         \
        (const __attribute__((address_space(1))) void*)gA_,                   \
        (__attribute__((address_space(3))) void*)&As[(w * 32) * 32],          \
        16, 0, 0);                                                            \
    __builtin_amdgcn_global_load_lds(                                         \
        (const __attribute__((address_space(1))) void*)(gA_ + (size_t)16 * 1024), \
        (__attribute__((address_space(3))) void*)&As[(w * 32 + 16) * 32],     \
        16, 0, 0);                                                            \
    __builtin_amdgcn_global_load_lds(                                         \
        (const __attribute__((address_space(1))) void*)gB_,                   \
        (__attribute__((address_space(3))) void*)&Bs[(w * 32) * 32],          \
        16, 0, 0);                                                            \
    __builtin_amdgcn_global_load_lds(                                         \
        (const __attribute__((address_space(1))) void*)(gB_ + (size_t)16 * 1024), \
        (__attribute__((address_space(3))) void*)&Bs[(w * 32 + 16) * 32],     \
        16, 0, 0);                                                            \
  } while (0)

// 10 ds_read_b128 feed 16 MFMA16; compiler schedules lgkmcnt fine-grained.
#define COMPUTE()                                                             \
  do {                                                                        \
    bf16x8 af[2], bfr[8];                                                     \
    _Pragma("unroll")                                                         \
    for (int fi = 0; fi < 2; ++fi)                                            \
      af[fi] = *(const bf16x8*)&As[(frowA + fi * 16) * 32 + fofs];            \
    _Pragma("unroll")                                                         \
    for (int fj = 0; fj < 8; ++fj)                                            \
      bfr[fj] = *(const bf16x8*)&Bs[(frowB + fj * 16) * 32 + fofs];           \
    __builtin_amdgcn_s_setprio(1);                                            \
    _Pragma("unroll")                                                         \
    for (int fi = 0; fi < 2; ++fi)                                            \
      _Pragma("unroll")                                                       \
      for (int fj = 0; fj < 8; ++fj)                                          \
        acc[fi][fj] = __builtin_amdgcn_mfma_f32_16x16x32_bf16(                \
            bfr[fj], af[fi], acc[fi][fj], 0, 0, 0);                           \
    __builtin_amdgcn_s_setprio(0);                                            \
  } while (0)

// grid: (64, 32) = 2048 blocks x 256 threads (~4 blocks/CU, 16 waves/CU).
// blockIdx.x -> xcd = bx&7; window = xcd*8 + ((bx>>3)&7) [XCD owns 8
// windows = 1024 B-cols = 2 MB L2-resident]; rowtile = blockIdx.y.
// Block tile 128 rows x 128 cols; wave w owns rows [w*32, w*32+32) via
// 2 fi x 8 fj 16x16 MFMA tiles. K-loop: m97 2-barrier drain per BK=32
// slice, single LDS buffer, compiler-scheduled waitcnts.
__global__ __launch_bounds__(256) void screen11_kernel(
    const unsigned short* __restrict__ Abf, const unsigned short* __restrict__ Bbf,
    const float* __restrict__ y2g,
    float* __restrict__ cand_s, int* __restrict__ cand_i) {
  __shared__ unsigned short As[128 * 32];  // 8 KB
  __shared__ unsigned short Bs[128 * 32];  // 8 KB

  const int tid = threadIdx.x;
  const int w = tid >> 6;        // 0..3
  const int lane = tid & 63;

  const int bx = blockIdx.x;                        // 0..63
  const int window = (bx & 7) * 8 + ((bx >> 3) & 7);  // 0..63
  const int r0 = blockIdx.y * 128;
  const int c0 = window * 128;

  // staging: lane -> LDS slot (16 rows per glds), swizzle on global source
  const int srow = lane >> 2;                          // 0..15
  const int sofs = ((lane & 3) ^ ((lane >> 3) & 3)) * 8;

  // fragment reads: LDS col = kc ^ ((row>>1)&3), kc = lane>>4 (verified
  // 0-conflict pattern from screen6/8/10)
  const int frowA = w * 32 + (lane & 15);
  const int frowB = lane & 15;
  const int fofs = ((lane >> 4) ^ ((lane >> 1) & 3)) * 8;
  const int cgrp = (lane >> 4) * 4;

  f32x4 acc[2][8];
#pragma unroll
  for (int fi = 0; fi < 2; ++fi)
#pragma unroll
    for (int fj = 0; fj < 8; ++fj) {
      f32x4 z = {0.f, 0.f, 0.f, 0.f};
      acc[fi][fj] = z;
    }

  // m97 structure: 2 drain barriers per slice, compiler handles waitcnts.
#pragma unroll 1
  for (int t = 0; t < 32; ++t) {
    __syncthreads();   // previous COMPUTE's LDS reads complete
    STAGE(t);
    __syncthreads();   // glds staged & visible (compiler drains vmcnt)
    COMPUTE();
  }

  // barrier-free epilogue. Lane's cands: row = r0 + w*32 + fi*16 + (lane&15),
  // col = c0 + fj*16 + cgrp + reg. y2 read directly from global (L2-hot).
#pragma unroll
  for (int fi = 0; fi < 2; ++fi) {
    float ls[8];
    int li[8];
#pragma unroll
    for (int j = 0; j < 8; ++j) { ls[j] = SENTINEL; li[j] = 0x7fffffff; }
    const int cb = c0 + cgrp;
#pragma unroll
    for (int fj = 0; fj < 8; ++fj) {
      const float4 y2q = *(const float4*)&y2g[c0 + fj * 16 + cgrp];
#pragma unroll
      for (int reg = 0; reg < 4; ++reg) {
        const float s = y2q[reg] - 2.0f * acc[fi][fj][reg];
        if (s < ls[7]) {
          ls[7] = s; li[7] = cb + fj * 16 + reg;
#pragma unroll
          for (int j = 7; j > 0; --j) {
            if (ls[j] < ls[j - 1]) {
              const float tt = ls[j]; ls[j] = ls[j - 1]; ls[j - 1] = tt;
              const int u2 = li[j]; li[j] = li[j - 1]; li[j - 1] = u2;
            }
          }
        }
      }
    }
    // merge sorted 8-lists across the 4 lanes sharing this row
#pragma unroll
    for (int off = 16; off <= 32; off <<= 1) {
      float rs[8];
      int ri[8];
#pragma unroll
      for (int j = 0; j < 8; ++j) {
        rs[j] = __shfl_xor(ls[j], off, 64);
        ri[j] = __shfl_xor(li[j], off, 64);
      }
      float ms[8];
      int mi_[8];
#pragma unroll
      for (int i = 0; i < 8; ++i) {
        const bool tk = ls[i] < rs[7 - i];
        ms[i] = tk ? ls[i] : rs[7 - i];
        mi_[i] = tk ? li[i] : ri[7 - i];
      }
      CAS(ms[0], mi_[0], ms[4], mi_[4]);
      CAS(ms[1], mi_[1], ms[5], mi_[5]);
      CAS(ms[2], mi_[2], ms[6], mi_[6]);
      CAS(ms[3], mi_[3], ms[7], mi_[7]);
      CAS(ms[0], mi_[0], ms[2], mi_[2]);
      CAS(ms[1], mi_[1], ms[3], mi_[3]);
      CAS(ms[4], mi_[4], ms[6], mi_[6]);
      CAS(ms[5], mi_[5], ms[7], mi_[7]);
      CAS(ms[0], mi_[0], ms[1], mi_[1]);
      CAS(ms[2], mi_[2], ms[3], mi_[3]);
      CAS(ms[4], mi_[4], ms[5], mi_[5]);
      CAS(ms[6], mi_[6], ms[7], mi_[7]);
#pragma unroll
      for (int j = 0; j < 8; ++j) { ls[j] = ms[j]; li[j] = mi_[j]; }
    }
    if ((lane >> 4) == 0) {  // lanes 0..15 hold the merged per-row top-8
      const int row = r0 + w * 32 + fi * 16 + lane;
      const size_t base = ((size_t)row * 64 + window) * 8;
#pragma unroll
      for (int j = 0; j < 8; ++j) {
        cand_s[base + j] = ls[j];
        cand_i[base + j] = li[j];
      }
    }
  }
}

// 2 waves per row: grid N/2 blocks x 256 threads (4 waves = 2 rows x 2
// wave-halves). Lane loads sorted group `lane` (8 contiguous cands) ->
// 6-level butterfly bitonic keep-12 merge -> exact fp32 rescore with B
// fragments kept in registers -> top-8 -> weighted sum from registers.
__global__ __launch_bounds__(256) void finalize6_kernel(
    const float* __restrict__ A, const float* __restrict__ B,
    const float* __restrict__ y2g,
    const float* __restrict__ cand_s, const int* __restrict__ cand_i,
    float* __restrict__ out) {
  const int tid = threadIdx.x;
  const int w = tid >> 6;
  const int lane = tid & 63;
  const int rloc = w >> 1;  // row within block
  const int wh = w & 1;     // wave-half along D
  const int n = blockIdx.x * 2 + rloc;
  __shared__ float comb[2][2][16];

  float s12[12];
  int i12[12];
  {
    const float4* cs = (const float4*)&cand_s[(size_t)n * 512 + lane * 8];
    const int4* cj = (const int4*)&cand_i[(size_t)n * 512 + lane * 8];
    const float4 sa = cs[0], sb = cs[1];
    const int4 ja = cj[0], jb = cj[1];
    s12[0] = sa.x; s12[1] = sa.y; s12[2] = sa.z; s12[3] = sa.w;
    s12[4] = sb.x; s12[5] = sb.y; s12[6] = sb.z; s12[7] = sb.w;
    i12[0] = ja.x; i12[1] = ja.y; i12[2] = ja.z; i12[3] = ja.w;
    i12[4] = jb.x; i12[5] = jb.y; i12[6] = jb.z; i12[7] = jb.w;
#pragma unroll
    for (int j = 8; j < 12; ++j) { s12[j] = SENTINEL; i12[j] = 0x7fffffff; }
  }

  // butterfly merge: sorted-12 + sorted-12 -> lowest-12 sorted.
#pragma unroll
  for (int off = 1; off <= 32; off <<= 1) {
    float rs[12];
    int ri[12];
#pragma unroll
    for (int j = 0; j < 12; ++j) {
      rs[j] = __shfl_xor(s12[j], off, 64);
      ri[j] = __shfl_xor(i12[j], off, 64);
    }
    float ms[12];
    int mj[12];
#pragma unroll
    for (int j = 0; j < 12; ++j) {
      const bool tke = s12[j] < rs[11 - j];
      ms[j] = tke ? s12[j] : rs[11 - j];
      mj[j] = tke ? i12[j] : ri[11 - j];
    }
    CAS(ms[0], mj[0], ms[8], mj[8]);  CAS(ms[1], mj[1], ms[9], mj[9]);
    CAS(ms[2], mj[2], ms[10], mj[10]); CAS(ms[3], mj[3], ms[11], mj[11]);
    CAS(ms[4], mj[4], ms[8], mj[8]);  CAS(ms[5], mj[5], ms[9], mj[9]);
    CAS(ms[6], mj[6], ms[10], mj[10]); CAS(ms[7], mj[7], ms[11], mj[11]);
    CAS(ms[0], mj[0], ms[2], mj[2]);  CAS(ms[1], mj[1], ms[3], mj[3]);
    CAS(ms[4], mj[4], ms[6], mj[6]);  CAS(ms[5], mj[5], ms[7], mj[7]);
    CAS(ms[8], mj[8], ms[10], mj[10]); CAS(ms[9], mj[9], ms[11], mj[11]);
    CAS(ms[0], mj[0], ms[1], mj[1]);  CAS(ms[2], mj[2], ms[3], mj[3]);
    CAS(ms[4], mj[4], ms[5], mj[5]);  CAS(ms[6], mj[6], ms[7], mj[7]);
    CAS(ms[8], mj[8], ms[9], mj[9]);  CAS(ms[10], mj[10], ms[11], mj[11]);
#pragma unroll
    for (int j = 0; j < 12; ++j) { s12[j] = ms[j]; i12[j] = mj[j]; }
  }
  // i12[0..11]: approx top-12 indices, identical in every lane/wave.

  // exact fp32 partial dots; B fragments RETAINED for the output sum.
  const float4* Arow = (const float4*)&A[(size_t)n * 1024];
  const int fbase = wh * 128 + lane * 2;
  float4 a4[2];
  a4[0] = Arow[fbase];
  a4[1] = Arow[fbase + 1];
  float4 bk0[12], bk1[12];
#pragma unroll
  for (int j = 0; j < 12; ++j) {
    const float4* Brow = (const float4*)&B[(size_t)i12[j] * 1024];
    bk0[j] = Brow[fbase];
    bk1[j] = Brow[fbase + 1];
  }
  float part[13];
  part[12] = a4[0].x * a4[0].x + a4[0].y * a4[0].y + a4[0].z * a4[0].z +
             a4[0].w * a4[0].w + a4[1].x * a4[1].x + a4[1].y * a4[1].y +
             a4[1].z * a4[1].z + a4[1].w * a4[1].w;
#pragma unroll
  for (int j = 0; j < 12; ++j) {
    part[j] = a4[0].x * bk0[j].x + a4[0].y * bk0[j].y + a4[0].z * bk0[j].z +
              a4[0].w * bk0[j].w;
    part[j] += a4[1].x * bk1[j].x + a4[1].y * bk1[j].y + a4[1].z * bk1[j].z +
               a4[1].w * bk1[j].w;
  }
#pragma unroll
  for (int r = 0; r < 13; ++r) {
#pragma unroll
    for (int off = 32; off >= 1; off >>= 1) part[r] += __shfl_xor(part[r], off, 64);
  }
  if (lane == 0) {
#pragma unroll
    for (int r = 0; r < 13; ++r) comb[rloc][wh][r] = part[r];
  }
  __syncthreads();
  float tot[13];
#pragma unroll
  for (int r = 0; r < 13; ++r) tot[r] = comb[rloc][0][r] + comb[rloc][1][r];

  // uniform redundant selection: top-8 by (d2, idx); weights land in wsel[]
  const float x2 = tot[12];
  float d2v[12];
  float wsel[12];
  bool used[12];
#pragma unroll
  for (int j = 0; j < 12; ++j) {
    d2v[j] = x2 + y2g[i12[j]] - 2.0f * tot[j];
    used[j] = false;
    wsel[j] = 0.0f;
  }
  float wsum = 0.0f;
  for (int k = 0; k < 8; ++k) {
    float bd = SENTINEL;
    int bi = 0x7fffffff, bslot = 0;
#pragma unroll
    for (int j = 0; j < 12; ++j) {
      if (used[j]) continue;
      const float d2 = d2v[j];
      if (d2 < bd || (d2 == bd && i12[j] < bi)) { bd = d2; bi = i12[j]; bslot = j; }
    }
    used[bslot] = true;
    const float d2c = fmaxf(bd, 1e-12f);
    const float wv = 1.0f / (sqrtf(d2c) + 0.1f);
    wsel[bslot] = wv;
    wsum += wv;
  }
  const float inv = 1.0f / wsum;

  float4 o0 = {0, 0, 0, 0}, o1 = {0, 0, 0, 0};
#pragma unroll
  for (int j = 0; j < 12; ++j) {
    const float wv = wsel[j];
    o0.x += wv * bk0[j].x; o0.y += wv * bk0[j].y;
    o0.z += wv * bk0[j].z; o0.w += wv * bk0[j].w;
    o1.x += wv * bk1[j].x; o1.y += wv * bk1[j].y;
    o1.z += wv * bk1[j].z; o1.w += wv * bk1[j].w;
  }
  o0.x *= inv; o0.y *= inv; o0.z *= inv; o0.w *= inv;
  o1.x *= inv; o1.y *= inv; o1.z *= inv; o1.w *= inv;
  float4* Orow = (float4*)&out[(size_t)n * 1024];
  Orow[fbase] = o0;
  Orow[fbase + 1] = o1;
}

// ---------------- fallback path (round-1, verified) ----------------
__global__ __launch_bounds__(256) void rownorm_kernel(
    const float* __restrict__ B, float* __restrict__ y2) {
  const int m = blockIdx.x;
  const int tid = threadIdx.x;
  __shared__ float red[256];
  const float4 v = *(const float4*)&B[(size_t)m * 1024 + tid * 4];
  red[tid] = v.x * v.x + v.y * v.y + v.z * v.z + v.w * v.w;
  __syncthreads();
  for (int s = 128; s > 0; s >>= 1) {
    if (tid < s) red[tid] += red[tid + s];
    __syncthreads();
  }
  if (tid == 0) y2[m] = red[0];
}

__global__ __launch_bounds__(256) void knn_chunk_kernel(
    const float* __restrict__ A, const float* __restrict__ B,
    const float* __restrict__ y2g,
    float* __restrict__ cand_s, int* __restrict__ cand_i) {
  __shared__ float As[BKK][68];
  __shared__ float Bs[BKK][68];
  __shared__ float Sc[64][65];

  const int tid = threadIdx.x;
  const int tx = tid & 15;
  const int ty = tid >> 4;
  const int r0 = blockIdx.y * 64;
  const int c0 = blockIdx.x * 1024;
  const int lrow = tid >> 3;
  const int lk = (tid & 7) * 4;

  float top_s[8];
  int top_i[8];
#pragma unroll
  for (int j = 0; j < 8; ++j) { top_s[j] = SENTINEL; top_i[j] = 0x7fffffff; }

  for (int tile = 0; tile < 16; ++tile) {
    const int cbase = c0 + tile * 64;
    float acc[4][4];
#pragma unroll
    for (int i = 0; i < 4; ++i)
#pragma unroll
      for (int j = 0; j < 4; ++j) acc[i][j] = 0.0f;

    for (int k0 = 0; k0 < 1024; k0 += BKK) {
      const float4 a0 = *(const float4*)&A[(size_t)(r0 + lrow) * 1024 + k0 + lk];
      const float4 a1 = *(const float4*)&A[(size_t)(r0 + lrow + 32) * 1024 + k0 + lk];
      const float4 b0 = *(const float4*)&B[(size_t)(cbase + lrow) * 1024 + k0 + lk];
      const float4 b1 = *(const float4*)&B[(size_t)(cbase + lrow + 32) * 1024 + k0 + lk];
      __syncthreads();
      As[lk + 0][lrow] = a0.x; As[lk + 1][lrow] = a0.y;
      As[lk + 2][lrow] = a0.z; As[lk + 3][lrow] = a0.w;
      As[lk + 0][lrow + 32] = a1.x; As[lk + 1][lrow + 32] = a1.y;
      As[lk + 2][lrow + 32] = a1.z; As[lk + 3][lrow + 32] = a1.w;
      Bs[lk + 0][lrow] = b0.x; Bs[lk + 1][lrow] = b0.y;
      Bs[lk + 2][lrow] = b0.z; Bs[lk + 3][lrow] = b0.w;
      Bs[lk + 0][lrow + 32] = b1.x; Bs[lk + 1][lrow + 32] = b1.y;
      Bs[lk + 2][lrow + 32] = b1.z; Bs[lk + 3][lrow + 32] = b1.w;
      __syncthreads();
#pragma unroll
      for (int kk = 0; kk < BKK; ++kk) {
        const float4 av = *(const float4*)&As[kk][ty * 4];
        const float4 bv = *(const float4*)&Bs[kk][tx * 4];
        acc[0][0] += av.x * bv.x; acc[0][1] += av.x * bv.y;
        acc[0][2] += av.x * bv.z; acc[0][3] += av.x * bv.w;
        acc[1][0] += av.y * bv.x; acc[1][1] += av.y * bv.y;
        acc[1][2] += av.y * bv.z; acc[1][3] += av.y * bv.w;
        acc[2][0] += av.z * bv.x; acc[2][1] += av.z * bv.y;
        acc[2][2] += av.z * bv.z; acc[2][3] += av.z * bv.w;
        acc[3][0] += av.w * bv.x; acc[3][1] += av.w * bv.y;
        acc[3][2] += av.w * bv.z; acc[3][3] += av.w * bv.w;
      }
    }
#pragma unroll
    for (int i = 0; i < 4; ++i) {
      const int row = ty * 4 + i;
#pragma unroll
      for (int j = 0; j < 4; ++j) {
        const int col = tx * 4 + j;
        Sc[row][col] = y2g[cbase + col] - 2.0f * acc[i][j];
      }
    }
    __syncthreads();
    if (tid < 64) {
      for (int c = 0; c < 64; ++c) {
        const float s = Sc[tid][c];
        if (s < top_s[7]) {
          top_s[7] = s; top_i[7] = cbase + c;
#pragma unroll
          for (int j = 7; j > 0; --j) {
            if (top_s[j] < top_s[j - 1]) {
              const float tss = top_s[j]; top_s[j] = top_s[j - 1]; top_s[j - 1] = tss;
              const int tii = top_i[j]; top_i[j] = top_i[j - 1]; top_i[j - 1] = tii;
            }
          }
        }
      }
    }
  }

  if (tid < 64) {
    const int n = r0 + tid;
    const int base = (n * gridDim.x + blockIdx.x) * 8;
#pragma unroll
    for (int j = 0; j < 8; ++j) {
      cand_s[base + j] = top_s[j];
      cand_i[base + j] = top_i[j];
    }
  }
}

__global__ __launch_bounds__(256) void finalize_kernel(
    const float* __restrict__ A, const float* __restrict__ B,
    const float* __restrict__ cand_s, const int* __restrict__ cand_i,
    float* __restrict__ out, int nchunks) {
  const int n = blockIdx.x;
  const int tid = threadIdx.x;
  __shared__ float red[256];
  __shared__ float ls[64];
  __shared__ int li[64];
  __shared__ float wsh2[8];
  __shared__ int wid[8];
  __shared__ float wsum_sh;

  const int ncand = nchunks * 8;
  const float4 a = *(const float4*)&A[(size_t)n * 1024 + tid * 4];
  red[tid] = a.x * a.x + a.y * a.y + a.z * a.z + a.w * a.w;
  if (tid < ncand) {
    ls[tid] = cand_s[n * ncand + tid];
    li[tid] = cand_i[n * ncand + tid];
  }
  __syncthreads();
  for (int s = 128; s > 0; s >>= 1) {
    if (tid < s) red[tid] += red[tid + s];
    __syncthreads();
  }
  if (tid == 0) {
    const float x2 = red[0];
    float wsum = 0.0f;
    for (int j = 0; j < 8; ++j) {
      float bs = SENTINEL;
      int bi = 0x7fffffff;
      int bp = 0;
      for (int c = 0; c < ncand; ++c) {
        const float s_ = ls[c];
        const int i_ = li[c];
        if (s_ < bs || (s_ == bs && i_ < bi)) { bs = s_; bi = i_; bp = c; }
      }
      ls[bp] = SENTINEL; li[bp] = 0x7fffffff;
      float d2 = x2 + bs;
      d2 = fmaxf(d2, 1e-12f);
      const float wkk = 1.0f / (sqrtf(d2) + 0.1f);
      wsh2[j] = wkk; wid[j] = bi;
      wsum += wkk;
    }
    wsum_sh = wsum;
  }
  __syncthreads();
  const float inv = 1.0f / wsum_sh;
  float ox = 0.0f, oy = 0.0f, oz = 0.0f, ow = 0.0f;
#pragma unroll
  for (int j = 0; j < 8; ++j) {
    const float wkk = wsh2[j];
    const float4 v = *(const float4*)&B[(size_t)wid[j] * 1024 + tid * 4];
    ox += wkk * v.x; oy += wkk * v.y; oz += wkk * v.z; ow += wkk * v.w;
  }
  float4 o;
  o.x = ox * inv; o.y = oy * inv; o.z = oz * inv; o.w = ow * inv;
  *(float4*)&out[(size_t)n * 1024 + tid * 4] = o;
}

extern "C" void kernel_launch(void* const* d_in, const int* in_sizes, int n_in,
                              void* d_out, int out_size, void* d_ws, size_t ws_size,
                              hipStream_t stream) {
  const float* A = (const float*)d_in[0];
  const float* Bm = (const float*)d_in[1];
  const int D = 1024;
  const int N = in_sizes[0] / D;  // 4096
  const int M = in_sizes[1] / D;  // 8192

  const size_t needA = (size_t)N * D * 2;
  const size_t needB = (size_t)M * D * 2;
  const size_t needC = (size_t)N * 512 * 4;  // cand_s (== cand_i)
  const size_t need = needA + needB + (size_t)M * 4 + 2 * needC;

  if (ws_size >= need && M == 8192 && N % 128 == 0 && N % 2 == 0) {
    unsigned short* Abf = (unsigned short*)d_ws;
    unsigned short* Bbf = Abf + (size_t)N * D;
    float* y2 = (float*)(Bbf + (size_t)M * D);
    float* cand_s = y2 + M;
    int* cand_i = (int*)(cand_s + (size_t)N * 512);

    convert_all_kernel<<<N + M, 256, 0, stream>>>(A, Bm, Abf, Bbf, y2, N);
    dim3 g(64, N / 128);
    screen11_kernel<<<g, 256, 0, stream>>>(Abf, Bbf, y2, cand_s, cand_i);
    finalize6_kernel<<<N / 2, 256, 0, stream>>>(A, Bm, y2, cand_s, cand_i,
                                                (float*)d_out);
  } else {
    float* y2 = (float*)d_ws;
    float* cand_s = y2 + M;
    int* cand_i = (int*)(cand_s + (size_t)N * 64);
    rownorm_kernel<<<M, 256, 0, stream>>>(Bm, y2);
    dim3 gridB(M / 1024, N / 64);
    knn_chunk_kernel<<<gridB, 256, 0, stream>>>(A, Bm, y2, cand_s, cand_i);
    finalize_kernel<<<N, 256, 0, stream>>>(A, Bm, cand_s, cand_i, (float*)d_out, M / 1024);
  }
}

// Round 9
// 348.200 us; speedup vs baseline: 1.1413x; 1.0049x over previous
//
#include <hip/hip_runtime.h>

// KNN (K=8) + inverse-distance-weighted average, MFMA screening version.
// data1: [N=4096, D=1024] fp32, data2: [M=8192, D=1024] fp32, out: [N, D] fp32.
//
// Fast path:
//  1) convert_all: A -> bf16; B -> bf16 fused with y2[m]=||B[m]||^2
//  2) screen12: bf16 16x16x32 MFMA GEMM, plain m97 sync (R8: plain beat
//     scaffolded 201 vs 272 at same geometry). R8 occupancy lesson: total
//     unified regs must be <=128 (occupancy steps at 64/128/256; screen11's
//     88+64=152 -> 2 waves/SIMD -> 22%). This kernel: wave tile 64x64
//     (a=b=4): 8 ds_read per 16 MFMA (0.5 ds/MFMA, best economy at 64
//     AGPR), lean 16-score epilogue -> target <=128 total regs -> 4
//     waves/SIMD. Block 128x128, 4 waves 2x2. Cross-wave col-half merge via
//     padded LDS (stride 17, conflict-free) + 128-thread register merge;
//     candidate layout bit-identical to screen5..11 (64 sorted groups of
//     8 per row). XCD swizzle: XCD owns 8 windows -> 2 MB B L2-resident.
//  3) finalize6: 2 waves per row; 512 sorted-8 groups -> 6-level butterfly
//     bitonic keep-12 merge -> EXACT fp32 rescore with B fragments RETAINED
//     in registers -> top-8 by (d2, idx) -> w = 1/(sqrt(max(d2,1e-12))+0.1)
//     -> weighted sum from registers.
// Fallback (small ws): round-1 pure-fp32 path (verified correct).

typedef short bf16x8 __attribute__((ext_vector_type(8)));
typedef float f32x4 __attribute__((ext_vector_type(4)));

#define SENTINEL 1e30f
#define BKK 32

static __device__ __forceinline__ unsigned short f2bf(float f) {
  unsigned u = __float_as_uint(f);
  return (unsigned short)((u + 0x7fffu + ((u >> 16) & 1u)) >> 16);
}

// ---------------- fast path kernels ----------------
// grid: N + M blocks. bid < N: convert A row. else: convert B row + norm.
__global__ __launch_bounds__(256) void convert_all_kernel(
    const float* __restrict__ A, const float* __restrict__ B,
    unsigned short* __restrict__ Abf, unsigned short* __restrict__ Bbf,
    float* __restrict__ y2, int N) {
  const int bid = blockIdx.x;
  const int tid = threadIdx.x;
  if (bid < N) {
    const float4 v = ((const float4*)&A[(size_t)bid * 1024])[tid];
    ushort4 o;
    o.x = f2bf(v.x); o.y = f2bf(v.y); o.z = f2bf(v.z); o.w = f2bf(v.w);
    ((ushort4*)&Abf[(size_t)bid * 1024])[tid] = o;
  } else {
    const int m = bid - N;
    __shared__ float red[256];
    const float4 v = ((const float4*)&B[(size_t)m * 1024])[tid];
    ushort4 o;
    o.x = f2bf(v.x); o.y = f2bf(v.y); o.z = f2bf(v.z); o.w = f2bf(v.w);
    ((ushort4*)&Bbf[(size_t)m * 1024])[tid] = o;
    red[tid] = v.x * v.x + v.y * v.y + v.z * v.z + v.w * v.w;
    __syncthreads();
    for (int s = 128; s > 0; s >>= 1) {
      if (tid < s) red[tid] += red[tid + s];
      __syncthreads();
    }
    if (tid == 0) y2[m] = red[0];
  }
}

// ascending compare-exchange on (s, i) register pairs
#define CAS(sa, ia, sb, ib)                         \
  do {                                              \
    if ((sa) > (sb)) {                              \
      const float _t = (sa); (sa) = (sb); (sb) = _t;\
      const int _u = (ia); (ia) = (ib); (ib) = _u;  \
    }                                               \
  } while (0)

// stage k-slice sk (k0 = sk*32) into the single LDS buffer.
// Wave w stages A rows [w*32,w*32+32) and B rows [w*32,w*32+32): 4 glds.
#define STAGE(sk)                                                             \
  do {                                                                        \
    const unsigned short* gA_ =                                               \
        Abf + (size_t)(r0 + w * 32 + srow) * 1024 + (sk) * 32 + sofs;         \
    const unsigned short* gB_ =                                               \
        Bbf + (size_t)(c0 + w * 32 + srow) * 1024 + (sk) * 32 + sofs;         \
    __builtin_amdgcn_global_load_lds(                                         \
        (const __attribute__((address_space(1))) void*)gA_,                   \
        (__attribute__((address_space(3))) void*)&As[(w * 32) * 32],          \
        16, 0, 0);                                                            \
    __builtin_amdgcn_global_load_lds(                                         \
        (const __attribute__((address_space(1))) void*)(gA_ + (size_t)16 * 1024), \
        (__attribute__((address_space(3))) void*)&As[(w * 32 + 16) * 32],     \
        16, 0, 0);                                                            \
    __builtin_amdgcn_global_load_lds(                                         \
        (const __attribute__((address_space(1))) void*)gB_,                   \
        (__attribute__((address_space(3))) void*)&Bs[(w * 32) * 32],          \
        16, 0, 0);                                                            \
    __builtin_amdgcn_global_load_lds(                                         \
        (const __attribute__((address_space(1))) void*)(gB_ + (size_t)16 * 1024), \
        (__attribute__((address_space(3))) void*)&Bs[(w * 32 + 16) * 32],     \
        16, 0, 0);                                                            \
  } while (0)

// 8 ds_read_b128 feed 16 MFMA16 (wave tile 64x64, a=b=4).
#define COMPUTE()                                                             \
  do {                                                                        \
    bf16x8 af[4], bfr[4];                                                     \
    _Pragma("unroll")                                                         \
    for (int fi = 0; fi < 4; ++fi)                                            \
      af[fi] = *(const bf16x8*)&As[(frowA + fi * 16) * 32 + fofs];            \
    _Pragma("unroll")                                                         \
    for (int fj = 0; fj < 4; ++fj)                                            \
      bfr[fj] = *(const bf16x8*)&Bs[(frowB + fj * 16) * 32 + fofs];           \
    __builtin_amdgcn_s_setprio(1);                                            \
    _Pragma("unroll")                                                         \
    for (int fi = 0; fi < 4; ++fi)                                            \
      _Pragma("unroll")                                                       \
      for (int fj = 0; fj < 4; ++fj)                                          \
        acc[fi][fj] = __builtin_amdgcn_mfma_f32_16x16x32_bf16(                \
            bfr[fj], af[fi], acc[fi][fj], 0, 0, 0);                           \
    __builtin_amdgcn_s_setprio(0);                                            \
  } while (0)

// grid: (64, 32) = 2048 blocks x 256 threads. blockIdx.x -> xcd = bx&7;
// window = xcd*8 + ((bx>>3)&7) [XCD owns 8 windows = 1024 B-cols = 2 MB
// L2-resident]; rowtile = blockIdx.y. Block tile 128x128; wave (wr,wc)
// owns rows [wr*64,+64) x cols [wc*64,+64) via 4x4 16x16 MFMA tiles.
// K-loop: m97 2-barrier drain per BK=32 slice, single LDS buffer.
// Epilogue: per-row top-8 of each 64-col half -> LDS (stride-17 pad) ->
// 128-thread merge of halves -> sorted top-8 per row per 128-col window.
__global__ __launch_bounds__(256) void screen12_kernel(
    const unsigned short* __restrict__ Abf, const unsigned short* __restrict__ Bbf,
    const float* __restrict__ y2g,
    float* __restrict__ cand_s, int* __restrict__ cand_i) {
  __shared__ unsigned short As[128 * 32];  // 8 KB
  __shared__ unsigned short Bs[128 * 32];  // 8 KB
  __shared__ float mrg_s[128 * 17];        // 8.5 KB (stride 17: conflict-free)
  __shared__ int mrg_i[128 * 17];          // 8.5 KB

  const int tid = threadIdx.x;
  const int w = tid >> 6;        // 0..3
  const int lane = tid & 63;
  const int wr = w >> 1;         // row half
  const int wc = w & 1;          // col half

  const int bx = blockIdx.x;                        // 0..63
  const int window = (bx & 7) * 8 + ((bx >> 3) & 7);  // 0..63
  const int r0 = blockIdx.y * 128;
  const int c0 = window * 128;

  // staging: lane -> LDS slot (16 rows per glds), swizzle on global source
  const int srow = lane >> 2;                          // 0..15
  const int sofs = ((lane & 3) ^ ((lane >> 3) & 3)) * 8;

  // fragment reads: LDS col = kc ^ ((row>>1)&3), kc = lane>>4 (verified
  // 0-conflict pattern from screen6/8/10/11)
  const int frowA = wr * 64 + (lane & 15);
  const int frowB = wc * 64 + (lane & 15);
  const int fofs = ((lane >> 4) ^ ((lane >> 1) & 3)) * 8;
  const int cgrp = (lane >> 4) * 4;

  f32x4 acc[4][4];
#pragma unroll
  for (int fi = 0; fi < 4; ++fi)
#pragma unroll
    for (int fj = 0; fj < 4; ++fj) {
      f32x4 z = {0.f, 0.f, 0.f, 0.f};
      acc[fi][fj] = z;
    }

  // m97 structure: 2 drain barriers per slice, compiler handles waitcnts.
#pragma unroll 1
  for (int t = 0; t < 32; ++t) {
    __syncthreads();   // previous COMPUTE's LDS reads complete
    STAGE(t);
    __syncthreads();   // glds staged & visible (compiler drains vmcnt)
    COMPUTE();
  }

  // epilogue stage 1: per fi, per-lane top-8 of 16 scores, then merge the
  // 4 lanes sharing a row -> lanes 0..15 hold the row's 64-col-half top-8.
#pragma unroll
  for (int fi = 0; fi < 4; ++fi) {
    float ls[8];
    int li[8];
#pragma unroll
    for (int j = 0; j < 8; ++j) { ls[j] = SENTINEL; li[j] = 0x7fffffff; }
    const int cb = c0 + wc * 64 + cgrp;
#pragma unroll
    for (int fj = 0; fj < 4; ++fj) {
      const float4 y2q = *(const float4*)&y2g[c0 + wc * 64 + fj * 16 + cgrp];
#pragma unroll
      for (int reg = 0; reg < 4; ++reg) {
        const float s = y2q[reg] - 2.0f * acc[fi][fj][reg];
        if (s < ls[7]) {
          ls[7] = s; li[7] = cb + fj * 16 + reg;
#pragma unroll
          for (int j = 7; j > 0; --j) {
            if (ls[j] < ls[j - 1]) {
              const float tt = ls[j]; ls[j] = ls[j - 1]; ls[j - 1] = tt;
              const int u2 = li[j]; li[j] = li[j - 1]; li[j - 1] = u2;
            }
          }
        }
      }
    }
    // merge sorted 8-lists across the 4 lanes sharing this row
#pragma unroll
    for (int off = 16; off <= 32; off <<= 1) {
      float rs[8];
      int ri[8];
#pragma unroll
      for (int j = 0; j < 8; ++j) {
        rs[j] = __shfl_xor(ls[j], off, 64);
        ri[j] = __shfl_xor(li[j], off, 64);
      }
      float ms[8];
      int mi_[8];
#pragma unroll
      for (int i = 0; i < 8; ++i) {
        const bool tk = ls[i] < rs[7 - i];
        ms[i] = tk ? ls[i] : rs[7 - i];
        mi_[i] = tk ? li[i] : ri[7 - i];
      }
      CAS(ms[0], mi_[0], ms[4], mi_[4]);
      CAS(ms[1], mi_[1], ms[5], mi_[5]);
      CAS(ms[2], mi_[2], ms[6], mi_[6]);
      CAS(ms[3], mi_[3], ms[7], mi_[7]);
      CAS(ms[0], mi_[0], ms[2], mi_[2]);
      CAS(ms[1], mi_[1], ms[3], mi_[3]);
      CAS(ms[4], mi_[4], ms[6], mi_[6]);
      CAS(ms[5], mi_[5], ms[7], mi_[7]);
      CAS(ms[0], mi_[0], ms[1], mi_[1]);
      CAS(ms[2], mi_[2], ms[3], mi_[3]);
      CAS(ms[4], mi_[4], ms[5], mi_[5]);
      CAS(ms[6], mi_[6], ms[7], mi_[7]);
#pragma unroll
      for (int j = 0; j < 8; ++j) { ls[j] = ms[j]; li[j] = mi_[j]; }
    }
    if ((lane >> 4) == 0) {  // lanes 0..15: row half-window top-8 -> LDS
      const int rl = wr * 64 + fi * 16 + lane;
#pragma unroll
      for (int j = 0; j < 8; ++j) {
        mrg_s[rl * 17 + wc * 8 + j] = ls[j];
        mrg_i[rl * 17 + wc * 8 + j] = li[j];
      }
    }
  }
  __syncthreads();

  // epilogue stage 2: 128 threads merge the two sorted halves per row.
  if (tid < 128) {
    const int rl = tid;
    float a8[8], b8[8];
    int ai[8], bi8[8];
#pragma unroll
    for (int j = 0; j < 8; ++j) {
      a8[j] = mrg_s[rl * 17 + j];
      ai[j] = mrg_i[rl * 17 + j];
      b8[j] = mrg_s[rl * 17 + 8 + j];
      bi8[j] = mrg_i[rl * 17 + 8 + j];
    }
    float ms[8];
    int mi_[8];
#pragma unroll
    for (int i = 0; i < 8; ++i) {
      const bool tk = a8[i] < b8[7 - i];
      ms[i] = tk ? a8[i] : b8[7 - i];
      mi_[i] = tk ? ai[i] : bi8[7 - i];
    }
    CAS(ms[0], mi_[0], ms[4], mi_[4]);
    CAS(ms[1], mi_[1], ms[5], mi_[5]);
    CAS(ms[2], mi_[2], ms[6], mi_[6]);
    CAS(ms[3], mi_[3], ms[7], mi_[7]);
    CAS(ms[0], mi_[0], ms[2], mi_[2]);
    CAS(ms[1], mi_[1], ms[3], mi_[3]);
    CAS(ms[4], mi_[4], ms[6], mi_[6]);
    CAS(ms[5], mi_[5], ms[7], mi_[7]);
    CAS(ms[0], mi_[0], ms[1], mi_[1]);
    CAS(ms[2], mi_[2], ms[3], mi_[3]);
    CAS(ms[4], mi_[4], ms[5], mi_[5]);
    CAS(ms[6], mi_[6], ms[7], mi_[7]);
    const int row = r0 + rl;
    const size_t base = ((size_t)row * 64 + window) * 8;
#pragma unroll
    for (int j = 0; j < 8; ++j) {
      cand_s[base + j] = ms[j];
      cand_i[base + j] = mi_[j];
    }
  }
}

// 2 waves per row: grid N/2 blocks x 256 threads (4 waves = 2 rows x 2
// wave-halves). Lane loads sorted group `lane` (8 contiguous cands) ->
// 6-level butterfly bitonic keep-12 merge -> exact fp32 rescore with B
// fragments kept in registers -> top-8 -> weighted sum from registers.
__global__ __launch_bounds__(256) void finalize6_kernel(
    const float* __restrict__ A, const float* __restrict__ B,
    const float* __restrict__ y2g,
    const float* __restrict__ cand_s, const int* __restrict__ cand_i,
    float* __restrict__ out) {
  const int tid = threadIdx.x;
  const int w = tid >> 6;
  const int lane = tid & 63;
  const int rloc = w >> 1;  // row within block
  const int wh = w & 1;     // wave-half along D
  const int n = blockIdx.x * 2 + rloc;
  __shared__ float comb[2][2][16];

  float s12[12];
  int i12[12];
  {
    const float4* cs = (const float4*)&cand_s[(size_t)n * 512 + lane * 8];
    const int4* cj = (const int4*)&cand_i[(size_t)n * 512 + lane * 8];
    const float4 sa = cs[0], sb = cs[1];
    const int4 ja = cj[0], jb = cj[1];
    s12[0] = sa.x; s12[1] = sa.y; s12[2] = sa.z; s12[3] = sa.w;
    s12[4] = sb.x; s12[5] = sb.y; s12[6] = sb.z; s12[7] = sb.w;
    i12[0] = ja.x; i12[1] = ja.y; i12[2] = ja.z; i12[3] = ja.w;
    i12[4] = jb.x; i12[5] = jb.y; i12[6] = jb.z; i12[7] = jb.w;
#pragma unroll
    for (int j = 8; j < 12; ++j) { s12[j] = SENTINEL; i12[j] = 0x7fffffff; }
  }

  // butterfly merge: sorted-12 + sorted-12 -> lowest-12 sorted.
#pragma unroll
  for (int off = 1; off <= 32; off <<= 1) {
    float rs[12];
    int ri[12];
#pragma unroll
    for (int j = 0; j < 12; ++j) {
      rs[j] = __shfl_xor(s12[j], off, 64);
      ri[j] = __shfl_xor(i12[j], off, 64);
    }
    float ms[12];
    int mj[12];
#pragma unroll
    for (int j = 0; j < 12; ++j) {
      const bool tke = s12[j] < rs[11 - j];
      ms[j] = tke ? s12[j] : rs[11 - j];
      mj[j] = tke ? i12[j] : ri[11 - j];
    }
    CAS(ms[0], mj[0], ms[8], mj[8]);  CAS(ms[1], mj[1], ms[9], mj[9]);
    CAS(ms[2], mj[2], ms[10], mj[10]); CAS(ms[3], mj[3], ms[11], mj[11]);
    CAS(ms[4], mj[4], ms[8], mj[8]);  CAS(ms[5], mj[5], ms[9], mj[9]);
    CAS(ms[6], mj[6], ms[10], mj[10]); CAS(ms[7], mj[7], ms[11], mj[11]);
    CAS(ms[0], mj[0], ms[2], mj[2]);  CAS(ms[1], mj[1], ms[3], mj[3]);
    CAS(ms[4], mj[4], ms[6], mj[6]);  CAS(ms[5], mj[5], ms[7], mj[7]);
    CAS(ms[8], mj[8], ms[10], mj[10]); CAS(ms[9], mj[9], ms[11], mj[11]);
    CAS(ms[0], mj[0], ms[1], mj[1]);  CAS(ms[2], mj[2], ms[3], mj[3]);
    CAS(ms[4], mj[4], ms[5], mj[5]);  CAS(ms[6], mj[6], ms[7], mj[7]);
    CAS(ms[8], mj[8], ms[9], mj[9]);  CAS(ms[10], mj[10], ms[11], mj[11]);
#pragma unroll
    for (int j = 0; j < 12; ++j) { s12[j] = ms[j]; i12[j] = mj[j]; }
  }
  // i12[0..11]: approx top-12 indices, identical in every lane/wave.

  // exact fp32 partial dots; B fragments RETAINED for the output sum.
  const float4* Arow = (const float4*)&A[(size_t)n * 1024];
  const int fbase = wh * 128 + lane * 2;
  float4 a4[2];
  a4[0] = Arow[fbase];
  a4[1] = Arow[fbase + 1];
  float4 bk0[12], bk1[12];
#pragma unroll
  for (int j = 0; j < 12; ++j) {
    const float4* Brow = (const float4*)&B[(size_t)i12[j] * 1024];
    bk0[j] = Brow[fbase];
    bk1[j] = Brow[fbase + 1];
  }
  float part[13];
  part[12] = a4[0].x * a4[0].x + a4[0].y * a4[0].y + a4[0].z * a4[0].z +
             a4[0].w * a4[0].w + a4[1].x * a4[1].x + a4[1].y * a4[1].y +
             a4[1].z * a4[1].z + a4[1].w * a4[1].w;
#pragma unroll
  for (int j = 0; j < 12; ++j) {
    part[j] = a4[0].x * bk0[j].x + a4[0].y * bk0[j].y + a4[0].z * bk0[j].z +
              a4[0].w * bk0[j].w;
    part[j] += a4[1].x * bk1[j].x + a4[1].y * bk1[j].y + a4[1].z * bk1[j].z +
               a4[1].w * bk1[j].w;
  }
#pragma unroll
  for (int r = 0; r < 13; ++r) {
#pragma unroll
    for (int off = 32; off >= 1; off >>= 1) part[r] += __shfl_xor(part[r], off, 64);
  }
  if (lane == 0) {
#pragma unroll
    for (int r = 0; r < 13; ++r) comb[rloc][wh][r] = part[r];
  }
  __syncthreads();
  float tot[13];
#pragma unroll
  for (int r = 0; r < 13; ++r) tot[r] = comb[rloc][0][r] + comb[rloc][1][r];

  // uniform redundant selection: top-8 by (d2, idx); weights land in wsel[]
  const float x2 = tot[12];
  float d2v[12];
  float wsel[12];
  bool used[12];
#pragma unroll
  for (int j = 0; j < 12; ++j) {
    d2v[j] = x2 + y2g[i12[j]] - 2.0f * tot[j];
    used[j] = false;
    wsel[j] = 0.0f;
  }
  float wsum = 0.0f;
  for (int k = 0; k < 8; ++k) {
    float bd = SENTINEL;
    int bi = 0x7fffffff, bslot = 0;
#pragma unroll
    for (int j = 0; j < 12; ++j) {
      if (used[j]) continue;
      const float d2 = d2v[j];
      if (d2 < bd || (d2 == bd && i12[j] < bi)) { bd = d2; bi = i12[j]; bslot = j; }
    }
    used[bslot] = true;
    const float d2c = fmaxf(bd, 1e-12f);
    const float wv = 1.0f / (sqrtf(d2c) + 0.1f);
    wsel[bslot] = wv;
    wsum += wv;
  }
  const float inv = 1.0f / wsum;

  float4 o0 = {0, 0, 0, 0}, o1 = {0, 0, 0, 0};
#pragma unroll
  for (int j = 0; j < 12; ++j) {
    const float wv = wsel[j];
    o0.x += wv * bk0[j].x; o0.y += wv * bk0[j].y;
    o0.z += wv * bk0[j].z; o0.w += wv * bk0[j].w;
    o1.x += wv * bk1[j].x; o1.y += wv * bk1[j].y;
    o1.z += wv * bk1[j].z; o1.w += wv * bk1[j].w;
  }
  o0.x *= inv; o0.y *= inv; o0.z *= inv; o0.w *= inv;
  o1.x *= inv; o1.y *= inv; o1.z *= inv; o1.w *= inv;
  float4* Orow = (float4*)&out[(size_t)n * 1024];
  Orow[fbase] = o0;
  Orow[fbase + 1] = o1;
}

// ---------------- fallback path (round-1, verified) ----------------
__global__ __launch_bounds__(256) void rownorm_kernel(
    const float* __restrict__ B, float* __restrict__ y2) {
  const int m = blockIdx.x;
  const int tid = threadIdx.x;
  __shared__ float red[256];
  const float4 v = *(const float4*)&B[(size_t)m * 1024 + tid * 4];
  red[tid] = v.x * v.x + v.y * v.y + v.z * v.z + v.w * v.w;
  __syncthreads();
  for (int s = 128; s > 0; s >>= 1) {
    if (tid < s) red[tid] += red[tid + s];
    __syncthreads();
  }
  if (tid == 0) y2[m] = red[0];
}

__global__ __launch_bounds__(256) void knn_chunk_kernel(
    const float* __restrict__ A, const float* __restrict__ B,
    const float* __restrict__ y2g,
    float* __restrict__ cand_s, int* __restrict__ cand_i) {
  __shared__ float As[BKK][68];
  __shared__ float Bs[BKK][68];
  __shared__ float Sc[64][65];

  const int tid = threadIdx.x;
  const int tx = tid & 15;
  const int ty = tid >> 4;
  const int r0 = blockIdx.y * 64;
  const int c0 = blockIdx.x * 1024;
  const int lrow = tid >> 3;
  const int lk = (tid & 7) * 4;

  float top_s[8];
  int top_i[8];
#pragma unroll
  for (int j = 0; j < 8; ++j) { top_s[j] = SENTINEL; top_i[j] = 0x7fffffff; }

  for (int tile = 0; tile < 16; ++tile) {
    const int cbase = c0 + tile * 64;
    float acc[4][4];
#pragma unroll
    for (int i = 0; i < 4; ++i)
#pragma unroll
      for (int j = 0; j < 4; ++j) acc[i][j] = 0.0f;

    for (int k0 = 0; k0 < 1024; k0 += BKK) {
      const float4 a0 = *(const float4*)&A[(size_t)(r0 + lrow) * 1024 + k0 + lk];
      const float4 a1 = *(const float4*)&A[(size_t)(r0 + lrow + 32) * 1024 + k0 + lk];
      const float4 b0 = *(const float4*)&B[(size_t)(cbase + lrow) * 1024 + k0 + lk];
      const float4 b1 = *(const float4*)&B[(size_t)(cbase + lrow + 32) * 1024 + k0 + lk];
      __syncthreads();
      As[lk + 0][lrow] = a0.x; As[lk + 1][lrow] = a0.y;
      As[lk + 2][lrow] = a0.z; As[lk + 3][lrow] = a0.w;
      As[lk + 0][lrow + 32] = a1.x; As[lk + 1][lrow + 32] = a1.y;
      As[lk + 2][lrow + 32] = a1.z; As[lk + 3][lrow + 32] = a1.w;
      Bs[lk + 0][lrow] = b0.x; Bs[lk + 1][lrow] = b0.y;
      Bs[lk + 2][lrow] = b0.z; Bs[lk + 3][lrow] = b0.w;
      Bs[lk + 0][lrow + 32] = b1.x; Bs[lk + 1][lrow + 32] = b1.y;
      Bs[lk + 2][lrow + 32] = b1.z; Bs[lk + 3][lrow + 32] = b1.w;
      __syncthreads();
#pragma unroll
      for (int kk = 0; kk < BKK; ++kk) {
        const float4 av = *(const float4*)&As[kk][ty * 4];
        const float4 bv = *(const float4*)&Bs[kk][tx * 4];
        acc[0][0] += av.x * bv.x; acc[0][1] += av.x * bv.y;
        acc[0][2] += av.x * bv.z; acc[0][3] += av.x * bv.w;
        acc[1][0] += av.y * bv.x; acc[1][1] += av.y * bv.y;
        acc[1][2] += av.y * bv.z; acc[1][3] += av.y * bv.w;
        acc[2][0] += av.z * bv.x; acc[2][1] += av.z * bv.y;
        acc[2][2] += av.z * bv.z; acc[2][3] += av.z * bv.w;
        acc[3][0] += av.w * bv.x; acc[3][1] += av.w * bv.y;
        acc[3][2] += av.w * bv.z; acc[3][3] += av.w * bv.w;
      }
    }
#pragma unroll
    for (int i = 0; i < 4; ++i) {
      const int row = ty * 4 + i;
#pragma unroll
      for (int j = 0; j < 4; ++j) {
        const int col = tx * 4 + j;
        Sc[row][col] = y2g[cbase + col] - 2.0f * acc[i][j];
      }
    }
    __syncthreads();
    if (tid < 64) {
      for (int c = 0; c < 64; ++c) {
        const float s = Sc[tid][c];
        if (s < top_s[7]) {
          top_s[7] = s; top_i[7] = cbase + c;
#pragma unroll
          for (int j = 7; j > 0; --j) {
            if (top_s[j] < top_s[j - 1]) {
              const float tss = top_s[j]; top_s[j] = top_s[j - 1]; top_s[j - 1] = tss;
              const int tii = top_i[j]; top_i[j] = top_i[j - 1]; top_i[j - 1] = tii;
            }
          }
        }
      }
    }
  }

  if (tid < 64) {
    const int n = r0 + tid;
    const int base = (n * gridDim.x + blockIdx.x) * 8;
#pragma unroll
    for (int j = 0; j < 8; ++j) {
      cand_s[base + j] = top_s[j];
      cand_i[base + j] = top_i[j];
    }
  }
}

__global__ __launch_bounds__(256) void finalize_kernel(
    const float* __restrict__ A, const float* __restrict__ B,
    const float* __restrict__ cand_s, const int* __restrict__ cand_i,
    float* __restrict__ out, int nchunks) {
  const int n = blockIdx.x;
  const int tid = threadIdx.x;
  __shared__ float red[256];
  __shared__ float ls[64];
  __shared__ int li[64];
  __shared__ float wsh2[8];
  __shared__ int wid[8];
  __shared__ float wsum_sh;

  const int ncand = nchunks * 8;
  const float4 a = *(const float4*)&A[(size_t)n * 1024 + tid * 4];
  red[tid] = a.x * a.x + a.y * a.y + a.z * a.z + a.w * a.w;
  if (tid < ncand) {
    ls[tid] = cand_s[n * ncand + tid];
    li[tid] = cand_i[n * ncand + tid];
  }
  __syncthreads();
  for (int s = 128; s > 0; s >>= 1) {
    if (tid < s) red[tid] += red[tid + s];
    __syncthreads();
  }
  if (tid == 0) {
    const float x2 = red[0];
    float wsum = 0.0f;
    for (int j = 0; j < 8; ++j) {
      float bs = SENTINEL;
      int bi = 0x7fffffff;
      int bp = 0;
      for (int c = 0; c < ncand; ++c) {
        const float s_ = ls[c];
        const int i_ = li[c];
        if (s_ < bs || (s_ == bs && i_ < bi)) { bs = s_; bi = i_; bp = c; }
      }
      ls[bp] = SENTINEL; li[bp] = 0x7fffffff;
      float d2 = x2 + bs;
      d2 = fmaxf(d2, 1e-12f);
      const float wkk = 1.0f / (sqrtf(d2) + 0.1f);
      wsh2[j] = wkk; wid[j] = bi;
      wsum += wkk;
    }
    wsum_sh = wsum;
  }
  __syncthreads();
  const float inv = 1.0f / wsum_sh;
  float ox = 0.0f, oy = 0.0f, oz = 0.0f, ow = 0.0f;
#pragma unroll
  for (int j = 0; j < 8; ++j) {
    const float wkk = wsh2[j];
    const float4 v = *(const float4*)&B[(size_t)wid[j] * 1024 + tid * 4];
    ox += wkk * v.x; oy += wkk * v.y; oz += wkk * v.z; ow += wkk * v.w;
  }
  float4 o;
  o.x = ox * inv; o.y = oy * inv; o.z = oz * inv; o.w = ow * inv;
  *(float4*)&out[(size_t)n * 1024 + tid * 4] = o;
}

extern "C" void kernel_launch(void* const* d_in, const int* in_sizes, int n_in,
                              void* d_out, int out_size, void* d_ws, size_t ws_size,
                              hipStream_t stream) {
  const float* A = (const float*)d_in[0];
  const float* Bm = (const float*)d_in[1];
  const int D = 1024;
  const int N = in_sizes[0] / D;  // 4096
  const int M = in_sizes[1] / D;  // 8192

  const size_t needA = (size_t)N * D * 2;
  const size_t needB = (size_t)M * D * 2;
  const size_t needC = (size_t)N * 512 * 4;  // cand_s (== cand_i)
  const size_t need = needA + needB + (size_t)M * 4 + 2 * needC;

  if (ws_size >= need && M == 8192 && N % 128 == 0 && N % 2 == 0) {
    unsigned short* Abf = (unsigned short*)d_ws;
    unsigned short* Bbf = Abf + (size_t)N * D;
    float* y2 = (float*)(Bbf + (size_t)M * D);
    float* cand_s = y2 + M;
    int* cand_i = (int*)(cand_s + (size_t)N * 512);

    convert_all_kernel<<<N + M, 256, 0, stream>>>(A, Bm, Abf, Bbf, y2, N);
    dim3 g(64, N / 128);
    screen12_kernel<<<g, 256, 0, stream>>>(Abf, Bbf, y2, cand_s, cand_i);
    finalize6_kernel<<<N / 2, 256, 0, stream>>>(A, Bm, y2, cand_s, cand_i,
                                                (float*)d_out);
  } else {
    float* y2 = (float*)d_ws;
    float* cand_s = y2 + M;
    int* cand_i = (int*)(cand_s + (size_t)N * 64);
    rownorm_kernel<<<M, 256, 0, stream>>>(Bm, y2);
    dim3 gridB(M / 1024, N / 64);
    knn_chunk_kernel<<<gridB, 256, 0, stream>>>(A, Bm, y2, cand_s, cand_i);
    finalize_kernel<<<N, 256, 0, stream>>>(A, Bm, cand_s, cand_i, (float*)d_out, M / 1024);
  }
}

// Round 10
// 318.498 us; speedup vs baseline: 1.2477x; 1.0933x over previous
//
#include <hip/hip_runtime.h>

// KNN (K=8) + inverse-distance-weighted average, MFMA screening version.
// data1: [N=4096, D=1024] fp32, data2: [M=8192, D=1024] fp32, out: [N, D] fp32.
//
// Fast path:
//  1) convert_all: A -> bf16; B -> bf16 fused with y2[m]=||B[m]||^2
//  2) screen13: bf16 16x16x32 MFMA GEMM, plain m97 sync. Session dataset:
//     occupancy 4-vs-2 waves/SIMD is worth ~30us (screen8 170 vs screen11
//     201); ds-economy at LOW occupancy is worth ~0 (screen12). This kernel
//     combines both for the first time: block 64x128, 4 waves 2x2, wave
//     tile 32x64 -> acc[2][4]=32 AGPR + ~52 arch regs = ~84 <= 128 total
//     (4 waves/SIMD, screen8-class occupancy) AND 6 ds_read per 8 MFMA
//     (0.75 ds/MFMA vs screen8's 1.125; block ds_reads 36->24 per slice
//     via A-row reuse across col-half waves + B-row reuse across row-half
//     waves). Epilogue: screen12's verified two-stage half-merge (stride-17
//     LDS). Candidate layout bit-identical to screen5..12. XCD swizzle:
//     XCD owns 8 windows -> 2 MB B L2-resident.
//  3) finalize6: 2 waves per row; 512 sorted-8 groups -> 6-level butterfly
//     bitonic keep-12 merge -> EXACT fp32 rescore with B fragments RETAINED
//     in registers -> top-8 by (d2, idx) -> w = 1/(sqrt(max(d2,1e-12))+0.1)
//     -> weighted sum from registers.
// Fallback (small ws): round-1 pure-fp32 path (verified correct).

typedef short bf16x8 __attribute__((ext_vector_type(8)));
typedef float f32x4 __attribute__((ext_vector_type(4)));

#define SENTINEL 1e30f
#define BKK 32

static __device__ __forceinline__ unsigned short f2bf(float f) {
  unsigned u = __float_as_uint(f);
  return (unsigned short)((u + 0x7fffu + ((u >> 16) & 1u)) >> 16);
}

// ---------------- fast path kernels ----------------
// grid: N + M blocks. bid < N: convert A row. else: convert B row + norm.
__global__ __launch_bounds__(256) void convert_all_kernel(
    const float* __restrict__ A, const float* __restrict__ B,
    unsigned short* __restrict__ Abf, unsigned short* __restrict__ Bbf,
    float* __restrict__ y2, int N) {
  const int bid = blockIdx.x;
  const int tid = threadIdx.x;
  if (bid < N) {
    const float4 v = ((const float4*)&A[(size_t)bid * 1024])[tid];
    ushort4 o;
    o.x = f2bf(v.x); o.y = f2bf(v.y); o.z = f2bf(v.z); o.w = f2bf(v.w);
    ((ushort4*)&Abf[(size_t)bid * 1024])[tid] = o;
  } else {
    const int m = bid - N;
    __shared__ float red[256];
    const float4 v = ((const float4*)&B[(size_t)m * 1024])[tid];
    ushort4 o;
    o.x = f2bf(v.x); o.y = f2bf(v.y); o.z = f2bf(v.z); o.w = f2bf(v.w);
    ((ushort4*)&Bbf[(size_t)m * 1024])[tid] = o;
    red[tid] = v.x * v.x + v.y * v.y + v.z * v.z + v.w * v.w;
    __syncthreads();
    for (int s = 128; s > 0; s >>= 1) {
      if (tid < s) red[tid] += red[tid + s];
      __syncthreads();
    }
    if (tid == 0) y2[m] = red[0];
  }
}

// ascending compare-exchange on (s, i) register pairs
#define CAS(sa, ia, sb, ib)                         \
  do {                                              \
    if ((sa) > (sb)) {                              \
      const float _t = (sa); (sa) = (sb); (sb) = _t;\
      const int _u = (ia); (ia) = (ib); (ib) = _u;  \
    }                                               \
  } while (0)

// stage k-slice sk (k0 = sk*32) into the single LDS buffer.
// Wave w stages A rows [w*16,w*16+16) (1 glds) and B rows [w*32,w*32+32)
// (2 glds): 3 glds per wave (A: 64 rows, B: 128 rows per block).
#define STAGE(sk)                                                             \
  do {                                                                        \
    const unsigned short* gA_ =                                               \
        Abf + (size_t)(r0 + w * 16 + srow) * 1024 + (sk) * 32 + sofs;         \
    const unsigned short* gB_ =                                               \
        Bbf + (size_t)(c0 + w * 32 + srow) * 1024 + (sk) * 32 + sofs;         \
    __builtin_amdgcn_global_load_lds(                                         \
        (const __attribute__((address_space(1))) void*)gA_,                   \
        (__attribute__((address_space(3))) void*)&As[(w * 16) * 32],          \
        16, 0, 0);                                                            \
    __builtin_amdgcn_global_load_lds(                                         \
        (const __attribute__((address_space(1))) void*)gB_,                   \
        (__attribute__((address_space(3))) void*)&Bs[(w * 32) * 32],          \
        16, 0, 0);                                                            \
    __builtin_amdgcn_global_load_lds(                                         \
        (const __attribute__((address_space(1))) void*)(gB_ + (size_t)16 * 1024), \
        (__attribute__((address_space(3))) void*)&Bs[(w * 32 + 16) * 32],     \
        16, 0, 0);                                                            \
  } while (0)

// 6 ds_read_b128 feed 8 MFMA16 (wave tile 32x64, a=2,b=4; 0.75 ds/MFMA).
#define COMPUTE()                                                             \
  do {                                                                        \
    bf16x8 af[2], bfr[4];                                                     \
    _Pragma("unroll")                                                         \
    for (int fi = 0; fi < 2; ++fi)                                            \
      af[fi] = *(const bf16x8*)&As[(frowA + fi * 16) * 32 + fofs];            \
    _Pragma("unroll")                                                         \
    for (int fj = 0; fj < 4; ++fj)                                            \
      bfr[fj] = *(const bf16x8*)&Bs[(frowB + fj * 16) * 32 + fofs];           \
    __builtin_amdgcn_s_setprio(1);                                            \
    _Pragma("unroll")                                                         \
    for (int fi = 0; fi < 2; ++fi)                                            \
      _Pragma("unroll")                                                       \
      for (int fj = 0; fj < 4; ++fj)                                          \
        acc[fi][fj] = __builtin_amdgcn_mfma_f32_16x16x32_bf16(                \
            bfr[fj], af[fi], acc[fi][fj], 0, 0, 0);                           \
    __builtin_amdgcn_s_setprio(0);                                            \
  } while (0)

// grid: (64, N/64) blocks x 256 threads. blockIdx.x -> xcd = bx&7;
// window = xcd*8 + ((bx>>3)&7) [XCD owns 8 windows = 1024 B-cols = 2 MB
// L2-resident]; rowtile = blockIdx.y. Block tile 64 rows x 128 cols; wave
// (wr,wc) owns rows [wr*32,+32) x cols [wc*64,+64) via 2x4 16x16 MFMA
// tiles. K-loop: m97 2-barrier drain per BK=32 slice, single LDS buffer.
// Epilogue: per-row top-8 of each 64-col half -> LDS (stride-17 pad) ->
// 64-thread merge of halves -> sorted top-8 per row per 128-col window.
__global__ __launch_bounds__(256) void screen13_kernel(
    const unsigned short* __restrict__ Abf, const unsigned short* __restrict__ Bbf,
    const float* __restrict__ y2g,
    float* __restrict__ cand_s, int* __restrict__ cand_i) {
  __shared__ unsigned short As[64 * 32];   // 4 KB
  __shared__ unsigned short Bs[128 * 32];  // 8 KB
  __shared__ float mrg_s[64 * 17];         // 4.25 KB (stride 17: conflict-free)
  __shared__ int mrg_i[64 * 17];           // 4.25 KB

  const int tid = threadIdx.x;
  const int w = tid >> 6;        // 0..3
  const int lane = tid & 63;
  const int wr = w >> 1;         // row half (32 rows)
  const int wc = w & 1;          // col half (64 cols)

  const int bx = blockIdx.x;                        // 0..63
  const int window = (bx & 7) * 8 + ((bx >> 3) & 7);  // 0..63
  const int r0 = blockIdx.y * 64;
  const int c0 = window * 128;

  // staging: lane -> LDS slot (16 rows per glds), swizzle on global source
  const int srow = lane >> 2;                          // 0..15
  const int sofs = ((lane & 3) ^ ((lane >> 3) & 3)) * 8;

  // fragment reads: LDS col = kc ^ ((row>>1)&3), kc = lane>>4 (verified
  // 0-conflict pattern from screen6/8/10/11/12)
  const int frowA = wr * 32 + (lane & 15);
  const int frowB = wc * 64 + (lane & 15);
  const int fofs = ((lane >> 4) ^ ((lane >> 1) & 3)) * 8;
  const int cgrp = (lane >> 4) * 4;

  f32x4 acc[2][4];
#pragma unroll
  for (int fi = 0; fi < 2; ++fi)
#pragma unroll
    for (int fj = 0; fj < 4; ++fj) {
      f32x4 z = {0.f, 0.f, 0.f, 0.f};
      acc[fi][fj] = z;
    }

  // m97 structure: 2 drain barriers per slice, compiler handles waitcnts.
#pragma unroll 1
  for (int t = 0; t < 32; ++t) {
    __syncthreads();   // previous COMPUTE's LDS reads complete
    STAGE(t);
    __syncthreads();   // glds staged & visible (compiler drains vmcnt)
    COMPUTE();
  }

  // epilogue stage 1: per fi, per-lane top-8 of 16 scores, then merge the
  // 4 lanes sharing a row -> lanes 0..15 hold the row's 64-col-half top-8.
#pragma unroll
  for (int fi = 0; fi < 2; ++fi) {
    float ls[8];
    int li[8];
#pragma unroll
    for (int j = 0; j < 8; ++j) { ls[j] = SENTINEL; li[j] = 0x7fffffff; }
    const int cb = c0 + wc * 64 + cgrp;
#pragma unroll
    for (int fj = 0; fj < 4; ++fj) {
      const float4 y2q = *(const float4*)&y2g[c0 + wc * 64 + fj * 16 + cgrp];
#pragma unroll
      for (int reg = 0; reg < 4; ++reg) {
        const float s = y2q[reg] - 2.0f * acc[fi][fj][reg];
        if (s < ls[7]) {
          ls[7] = s; li[7] = cb + fj * 16 + reg;
#pragma unroll
          for (int j = 7; j > 0; --j) {
            if (ls[j] < ls[j - 1]) {
              const float tt = ls[j]; ls[j] = ls[j - 1]; ls[j - 1] = tt;
              const int u2 = li[j]; li[j] = li[j - 1]; li[j - 1] = u2;
            }
          }
        }
      }
    }
    // merge sorted 8-lists across the 4 lanes sharing this row
#pragma unroll
    for (int off = 16; off <= 32; off <<= 1) {
      float rs[8];
      int ri[8];
#pragma unroll
      for (int j = 0; j < 8; ++j) {
        rs[j] = __shfl_xor(ls[j], off, 64);
        ri[j] = __shfl_xor(li[j], off, 64);
      }
      float ms[8];
      int mi_[8];
#pragma unroll
      for (int i = 0; i < 8; ++i) {
        const bool tk = ls[i] < rs[7 - i];
        ms[i] = tk ? ls[i] : rs[7 - i];
        mi_[i] = tk ? li[i] : ri[7 - i];
      }
      CAS(ms[0], mi_[0], ms[4], mi_[4]);
      CAS(ms[1], mi_[1], ms[5], mi_[5]);
      CAS(ms[2], mi_[2], ms[6], mi_[6]);
      CAS(ms[3], mi_[3], ms[7], mi_[7]);
      CAS(ms[0], mi_[0], ms[2], mi_[2]);
      CAS(ms[1], mi_[1], ms[3], mi_[3]);
      CAS(ms[4], mi_[4], ms[6], mi_[6]);
      CAS(ms[5], mi_[5], ms[7], mi_[7]);
      CAS(ms[0], mi_[0], ms[1], mi_[1]);
      CAS(ms[2], mi_[2], ms[3], mi_[3]);
      CAS(ms[4], mi_[4], ms[5], mi_[5]);
      CAS(ms[6], mi_[6], ms[7], mi_[7]);
#pragma unroll
      for (int j = 0; j < 8; ++j) { ls[j] = ms[j]; li[j] = mi_[j]; }
    }
    if ((lane >> 4) == 0) {  // lanes 0..15: row half-window top-8 -> LDS
      const int rl = wr * 32 + fi * 16 + lane;
#pragma unroll
      for (int j = 0; j < 8; ++j) {
        mrg_s[rl * 17 + wc * 8 + j] = ls[j];
        mrg_i[rl * 17 + wc * 8 + j] = li[j];
      }
    }
  }
  __syncthreads();

  // epilogue stage 2: 64 threads merge the two sorted halves per row.
  if (tid < 64) {
    const int rl = tid;
    float a8[8], b8[8];
    int ai[8], bi8[8];
#pragma unroll
    for (int j = 0; j < 8; ++j) {
      a8[j] = mrg_s[rl * 17 + j];
      ai[j] = mrg_i[rl * 17 + j];
      b8[j] = mrg_s[rl * 17 + 8 + j];
      bi8[j] = mrg_i[rl * 17 + 8 + j];
    }
    float ms[8];
    int mi_[8];
#pragma unroll
    for (int i = 0; i < 8; ++i) {
      const bool tk = a8[i] < b8[7 - i];
      ms[i] = tk ? a8[i] : b8[7 - i];
      mi_[i] = tk ? ai[i] : bi8[7 - i];
    }
    CAS(ms[0], mi_[0], ms[4], mi_[4]);
    CAS(ms[1], mi_[1], ms[5], mi_[5]);
    CAS(ms[2], mi_[2], ms[6], mi_[6]);
    CAS(ms[3], mi_[3], ms[7], mi_[7]);
    CAS(ms[0], mi_[0], ms[2], mi_[2]);
    CAS(ms[1], mi_[1], ms[3], mi_[3]);
    CAS(ms[4], mi_[4], ms[6], mi_[6]);
    CAS(ms[5], mi_[5], ms[7], mi_[7]);
    CAS(ms[0], mi_[0], ms[1], mi_[1]);
    CAS(ms[2], mi_[2], ms[3], mi_[3]);
    CAS(ms[4], mi_[4], ms[5], mi_[5]);
    CAS(ms[6], mi_[6], ms[7], mi_[7]);
    const int row = r0 + rl;
    const size_t base = ((size_t)row * 64 + window) * 8;
#pragma unroll
    for (int j = 0; j < 8; ++j) {
      cand_s[base + j] = ms[j];
      cand_i[base + j] = mi_[j];
    }
  }
}

// 2 waves per row: grid N/2 blocks x 256 threads (4 waves = 2 rows x 2
// wave-halves). Lane loads sorted group `lane` (8 contiguous cands) ->
// 6-level butterfly bitonic keep-12 merge -> exact fp32 rescore with B
// fragments kept in registers -> top-8 -> weighted sum from registers.
__global__ __launch_bounds__(256) void finalize6_kernel(
    const float* __restrict__ A, const float* __restrict__ B,
    const float* __restrict__ y2g,
    const float* __restrict__ cand_s, const int* __restrict__ cand_i,
    float* __restrict__ out) {
  const int tid = threadIdx.x;
  const int w = tid >> 6;
  const int lane = tid & 63;
  const int rloc = w >> 1;  // row within block
  const int wh = w & 1;     // wave-half along D
  const int n = blockIdx.x * 2 + rloc;
  __shared__ float comb[2][2][16];

  float s12[12];
  int i12[12];
  {
    const float4* cs = (const float4*)&cand_s[(size_t)n * 512 + lane * 8];
    const int4* cj = (const int4*)&cand_i[(size_t)n * 512 + lane * 8];
    const float4 sa = cs[0], sb = cs[1];
    const int4 ja = cj[0], jb = cj[1];
    s12[0] = sa.x; s12[1] = sa.y; s12[2] = sa.z; s12[3] = sa.w;
    s12[4] = sb.x; s12[5] = sb.y; s12[6] = sb.z; s12[7] = sb.w;
    i12[0] = ja.x; i12[1] = ja.y; i12[2] = ja.z; i12[3] = ja.w;
    i12[4] = jb.x; i12[5] = jb.y; i12[6] = jb.z; i12[7] = jb.w;
#pragma unroll
    for (int j = 8; j < 12; ++j) { s12[j] = SENTINEL; i12[j] = 0x7fffffff; }
  }

  // butterfly merge: sorted-12 + sorted-12 -> lowest-12 sorted.
#pragma unroll
  for (int off = 1; off <= 32; off <<= 1) {
    float rs[12];
    int ri[12];
#pragma unroll
    for (int j = 0; j < 12; ++j) {
      rs[j] = __shfl_xor(s12[j], off, 64);
      ri[j] = __shfl_xor(i12[j], off, 64);
    }
    float ms[12];
    int mj[12];
#pragma unroll
    for (int j = 0; j < 12; ++j) {
      const bool tke = s12[j] < rs[11 - j];
      ms[j] = tke ? s12[j] : rs[11 - j];
      mj[j] = tke ? i12[j] : ri[11 - j];
    }
    CAS(ms[0], mj[0], ms[8], mj[8]);  CAS(ms[1], mj[1], ms[9], mj[9]);
    CAS(ms[2], mj[2], ms[10], mj[10]); CAS(ms[3], mj[3], ms[11], mj[11]);
    CAS(ms[4], mj[4], ms[8], mj[8]);  CAS(ms[5], mj[5], ms[9], mj[9]);
    CAS(ms[6], mj[6], ms[10], mj[10]); CAS(ms[7], mj[7], ms[11], mj[11]);
    CAS(ms[0], mj[0], ms[2], mj[2]);  CAS(ms[1], mj[1], ms[3], mj[3]);
    CAS(ms[4], mj[4], ms[6], mj[6]);  CAS(ms[5], mj[5], ms[7], mj[7]);
    CAS(ms[8], mj[8], ms[10], mj[10]); CAS(ms[9], mj[9], ms[11], mj[11]);
    CAS(ms[0], mj[0], ms[1], mj[1]);  CAS(ms[2], mj[2], ms[3], mj[3]);
    CAS(ms[4], mj[4], ms[5], mj[5]);  CAS(ms[6], mj[6], ms[7], mj[7]);
    CAS(ms[8], mj[8], ms[9], mj[9]);  CAS(ms[10], mj[10], ms[11], mj[11]);
#pragma unroll
    for (int j = 0; j < 12; ++j) { s12[j] = ms[j]; i12[j] = mj[j]; }
  }
  // i12[0..11]: approx top-12 indices, identical in every lane/wave.

  // exact fp32 partial dots; B fragments RETAINED for the output sum.
  const float4* Arow = (const float4*)&A[(size_t)n * 1024];
  const int fbase = wh * 128 + lane * 2;
  float4 a4[2];
  a4[0] = Arow[fbase];
  a4[1] = Arow[fbase + 1];
  float4 bk0[12], bk1[12];
#pragma unroll
  for (int j = 0; j < 12; ++j) {
    const float4* Brow = (const float4*)&B[(size_t)i12[j] * 1024];
    bk0[j] = Brow[fbase];
    bk1[j] = Brow[fbase + 1];
  }
  float part[13];
  part[12] = a4[0].x * a4[0].x + a4[0].y * a4[0].y + a4[0].z * a4[0].z +
             a4[0].w * a4[0].w + a4[1].x * a4[1].x + a4[1].y * a4[1].y +
             a4[1].z * a4[1].z + a4[1].w * a4[1].w;
#pragma unroll
  for (int j = 0; j < 12; ++j) {
    part[j] = a4[0].x * bk0[j].x + a4[0].y * bk0[j].y + a4[0].z * bk0[j].z +
              a4[0].w * bk0[j].w;
    part[j] += a4[1].x * bk1[j].x + a4[1].y * bk1[j].y + a4[1].z * bk1[j].z +
               a4[1].w * bk1[j].w;
  }
#pragma unroll
  for (int r = 0; r < 13; ++r) {
#pragma unroll
    for (int off = 32; off >= 1; off >>= 1) part[r] += __shfl_xor(part[r], off, 64);
  }
  if (lane == 0) {
#pragma unroll
    for (int r = 0; r < 13; ++r) comb[rloc][wh][r] = part[r];
  }
  __syncthreads();
  float tot[13];
#pragma unroll
  for (int r = 0; r < 13; ++r) tot[r] = comb[rloc][0][r] + comb[rloc][1][r];

  // uniform redundant selection: top-8 by (d2, idx); weights land in wsel[]
  const float x2 = tot[12];
  float d2v[12];
  float wsel[12];
  bool used[12];
#pragma unroll
  for (int j = 0; j < 12; ++j) {
    d2v[j] = x2 + y2g[i12[j]] - 2.0f * tot[j];
    used[j] = false;
    wsel[j] = 0.0f;
  }
  float wsum = 0.0f;
  for (int k = 0; k < 8; ++k) {
    float bd = SENTINEL;
    int bi = 0x7fffffff, bslot = 0;
#pragma unroll
    for (int j = 0; j < 12; ++j) {
      if (used[j]) continue;
      const float d2 = d2v[j];
      if (d2 < bd || (d2 == bd && i12[j] < bi)) { bd = d2; bi = i12[j]; bslot = j; }
    }
    used[bslot] = true;
    const float d2c = fmaxf(bd, 1e-12f);
    const float wv = 1.0f / (sqrtf(d2c) + 0.1f);
    wsel[bslot] = wv;
    wsum += wv;
  }
  const float inv = 1.0f / wsum;

  float4 o0 = {0, 0, 0, 0}, o1 = {0, 0, 0, 0};
#pragma unroll
  for (int j = 0; j < 12; ++j) {
    const float wv = wsel[j];
    o0.x += wv * bk0[j].x; o0.y += wv * bk0[j].y;
    o0.z += wv * bk0[j].z; o0.w += wv * bk0[j].w;
    o1.x += wv * bk1[j].x; o1.y += wv * bk1[j].y;
    o1.z += wv * bk1[j].z; o1.w += wv * bk1[j].w;
  }
  o0.x *= inv; o0.y *= inv; o0.z *= inv; o0.w *= inv;
  o1.x *= inv; o1.y *= inv; o1.z *= inv; o1.w *= inv;
  float4* Orow = (float4*)&out[(size_t)n * 1024];
  Orow[fbase] = o0;
  Orow[fbase + 1] = o1;
}

// ---------------- fallback path (round-1, verified) ----------------
__global__ __launch_bounds__(256) void rownorm_kernel(
    const float* __restrict__ B, float* __restrict__ y2) {
  const int m = blockIdx.x;
  const int tid = threadIdx.x;
  __shared__ float red[256];
  const float4 v = *(const float4*)&B[(size_t)m * 1024 + tid * 4];
  red[tid] = v.x * v.x + v.y * v.y + v.z * v.z + v.w * v.w;
  __syncthreads();
  for (int s = 128; s > 0; s >>= 1) {
    if (tid < s) red[tid] += red[tid + s];
    __syncthreads();
  }
  if (tid == 0) y2[m] = red[0];
}

__global__ __launch_bounds__(256) void knn_chunk_kernel(
    const float* __restrict__ A, const float* __restrict__ B,
    const float* __restrict__ y2g,
    float* __restrict__ cand_s, int* __restrict__ cand_i) {
  __shared__ float As[BKK][68];
  __shared__ float Bs[BKK][68];
  __shared__ float Sc[64][65];

  const int tid = threadIdx.x;
  const int tx = tid & 15;
  const int ty = tid >> 4;
  const int r0 = blockIdx.y * 64;
  const int c0 = blockIdx.x * 1024;
  const int lrow = tid >> 3;
  const int lk = (tid & 7) * 4;

  float top_s[8];
  int top_i[8];
#pragma unroll
  for (int j = 0; j < 8; ++j) { top_s[j] = SENTINEL; top_i[j] = 0x7fffffff; }

  for (int tile = 0; tile < 16; ++tile) {
    const int cbase = c0 + tile * 64;
    float acc[4][4];
#pragma unroll
    for (int i = 0; i < 4; ++i)
#pragma unroll
      for (int j = 0; j < 4; ++j) acc[i][j] = 0.0f;

    for (int k0 = 0; k0 < 1024; k0 += BKK) {
      const float4 a0 = *(const float4*)&A[(size_t)(r0 + lrow) * 1024 + k0 + lk];
      const float4 a1 = *(const float4*)&A[(size_t)(r0 + lrow + 32) * 1024 + k0 + lk];
      const float4 b0 = *(const float4*)&B[(size_t)(cbase + lrow) * 1024 + k0 + lk];
      const float4 b1 = *(const float4*)&B[(size_t)(cbase + lrow + 32) * 1024 + k0 + lk];
      __syncthreads();
      As[lk + 0][lrow] = a0.x; As[lk + 1][lrow] = a0.y;
      As[lk + 2][lrow] = a0.z; As[lk + 3][lrow] = a0.w;
      As[lk + 0][lrow + 32] = a1.x; As[lk + 1][lrow + 32] = a1.y;
      As[lk + 2][lrow + 32] = a1.z; As[lk + 3][lrow + 32] = a1.w;
      Bs[lk + 0][lrow] = b0.x; Bs[lk + 1][lrow] = b0.y;
      Bs[lk + 2][lrow] = b0.z; Bs[lk + 3][lrow] = b0.w;
      Bs[lk + 0][lrow + 32] = b1.x; Bs[lk + 1][lrow + 32] = b1.y;
      Bs[lk + 2][lrow + 32] = b1.z; Bs[lk + 3][lrow + 32] = b1.w;
      __syncthreads();
#pragma unroll
      for (int kk = 0; kk < BKK; ++kk) {
        const float4 av = *(const float4*)&As[kk][ty * 4];
        const float4 bv = *(const float4*)&Bs[kk][tx * 4];
        acc[0][0] += av.x * bv.x; acc[0][1] += av.x * bv.y;
        acc[0][2] += av.x * bv.z; acc[0][3] += av.x * bv.w;
        acc[1][0] += av.y * bv.x; acc[1][1] += av.y * bv.y;
        acc[1][2] += av.y * bv.z; acc[1][3] += av.y * bv.w;
        acc[2][0] += av.z * bv.x; acc[2][1] += av.z * bv.y;
        acc[2][2] += av.z * bv.z; acc[2][3] += av.z * bv.w;
        acc[3][0] += av.w * bv.x; acc[3][1] += av.w * bv.y;
        acc[3][2] += av.w * bv.z; acc[3][3] += av.w * bv.w;
      }
    }
#pragma unroll
    for (int i = 0; i < 4; ++i) {
      const int row = ty * 4 + i;
#pragma unroll
      for (int j = 0; j < 4; ++j) {
        const int col = tx * 4 + j;
        Sc[row][col] = y2g[cbase + col] - 2.0f * acc[i][j];
      }
    }
    __syncthreads();
    if (tid < 64) {
      for (int c = 0; c < 64; ++c) {
        const float s = Sc[tid][c];
        if (s < top_s[7]) {
          top_s[7] = s; top_i[7] = cbase + c;
#pragma unroll
          for (int j = 7; j > 0; --j) {
            if (top_s[j] < top_s[j - 1]) {
              const float tss = top_s[j]; top_s[j] = top_s[j - 1]; top_s[j - 1] = tss;
              const int tii = top_i[j]; top_i[j] = top_i[j - 1]; top_i[j - 1] = tii;
            }
          }
        }
      }
    }
  }

  if (tid < 64) {
    const int n = r0 + tid;
    const int base = (n * gridDim.x + blockIdx.x) * 8;
#pragma unroll
    for (int j = 0; j < 8; ++j) {
      cand_s[base + j] = top_s[j];
      cand_i[base + j] = top_i[j];
    }
  }
}

__global__ __launch_bounds__(256) void finalize_kernel(
    const float* __restrict__ A, const float* __restrict__ B,
    const float* __restrict__ cand_s, const int* __restrict__ cand_i,
    float* __restrict__ out, int nchunks) {
  const int n = blockIdx.x;
  const int tid = threadIdx.x;
  __shared__ float red[256];
  __shared__ float ls[64];
  __shared__ int li[64];
  __shared__ float wsh2[8];
  __shared__ int wid[8];
  __shared__ float wsum_sh;

  const int ncand = nchunks * 8;
  const float4 a = *(const float4*)&A[(size_t)n * 1024 + tid * 4];
  red[tid] = a.x * a.x + a.y * a.y + a.z * a.z + a.w * a.w;
  if (tid < ncand) {
    ls[tid] = cand_s[n * ncand + tid];
    li[tid] = cand_i[n * ncand + tid];
  }
  __syncthreads();
  for (int s = 128; s > 0; s >>= 1) {
    if (tid < s) red[tid] += red[tid + s];
    __syncthreads();
  }
  if (tid == 0) {
    const float x2 = red[0];
    float wsum = 0.0f;
    for (int j = 0; j < 8; ++j) {
      float bs = SENTINEL;
      int bi = 0x7fffffff;
      int bp = 0;
      for (int c = 0; c < ncand; ++c) {
        const float s_ = ls[c];
        const int i_ = li[c];
        if (s_ < bs || (s_ == bs && i_ < bi)) { bs = s_; bi = i_; bp = c; }
      }
      ls[bp] = SENTINEL; li[bp] = 0x7fffffff;
      float d2 = x2 + bs;
      d2 = fmaxf(d2, 1e-12f);
      const float wkk = 1.0f / (sqrtf(d2) + 0.1f);
      wsh2[j] = wkk; wid[j] = bi;
      wsum += wkk;
    }
    wsum_sh = wsum;
  }
  __syncthreads();
  const float inv = 1.0f / wsum_sh;
  float ox = 0.0f, oy = 0.0f, oz = 0.0f, ow = 0.0f;
#pragma unroll
  for (int j = 0; j < 8; ++j) {
    const float wkk = wsh2[j];
    const float4 v = *(const float4*)&B[(size_t)wid[j] * 1024 + tid * 4];
    ox += wkk * v.x; oy += wkk * v.y; oz += wkk * v.z; ow += wkk * v.w;
  }
  float4 o;
  o.x = ox * inv; o.y = oy * inv; o.z = oz * inv; o.w = ow * inv;
  *(float4*)&out[(size_t)n * 1024 + tid * 4] = o;
}

extern "C" void kernel_launch(void* const* d_in, const int* in_sizes, int n_in,
                              void* d_out, int out_size, void* d_ws, size_t ws_size,
                              hipStream_t stream) {
  const float* A = (const float*)d_in[0];
  const float* Bm = (const float*)d_in[1];
  const int D = 1024;
  const int N = in_sizes[0] / D;  // 4096
  const int M = in_sizes[1] / D;  // 8192

  const size_t needA = (size_t)N * D * 2;
  const size_t needB = (size_t)M * D * 2;
  const size_t needC = (size_t)N * 512 * 4;  // cand_s (== cand_i)
  const size_t need = needA + needB + (size_t)M * 4 + 2 * needC;

  if (ws_size >= need && M == 8192 && N % 64 == 0 && N % 2 == 0) {
    unsigned short* Abf = (unsigned short*)d_ws;
    unsigned short* Bbf = Abf + (size_t)N * D;
    float* y2 = (float*)(Bbf + (size_t)M * D);
    float* cand_s = y2 + M;
    int* cand_i = (int*)(cand_s + (size_t)N * 512);

    convert_all_kernel<<<N + M, 256, 0, stream>>>(A, Bm, Abf, Bbf, y2, N);
    dim3 g(64, N / 64);
    screen13_kernel<<<g, 256, 0, stream>>>(Abf, Bbf, y2, cand_s, cand_i);
    finalize6_kernel<<<N / 2, 256, 0, stream>>>(A, Bm, y2, cand_s, cand_i,
                                                (float*)d_out);
  } else {
    float* y2 = (float*)d_ws;
    float* cand_s = y2 + M;
    int* cand_i = (int*)(cand_s + (size_t)N * 64);
    rownorm_kernel<<<M, 256, 0, stream>>>(Bm, y2);
    dim3 gridB(M / 1024, N / 64);
    knn_chunk_kernel<<<gridB, 256, 0, stream>>>(A, Bm, y2, cand_s, cand_i);
    finalize_kernel<<<N, 256, 0, stream>>>(A, Bm, cand_s, cand_i, (float*)d_out, M / 1024);
  }
}

// Round 11
// 308.237 us; speedup vs baseline: 1.2893x; 1.0333x over previous
//
#include <hip/hip_runtime.h>

// KNN (K=8) + inverse-distance-weighted average, MFMA screening version.
// data1: [N=4096, D=1024] fp32, data2: [M=8192, D=1024] fp32, out: [N, D] fp32.
//
// Fast path:
//  1) convert_all: A -> bf16; B -> bf16 fused with y2[m]=||B[m]||^2
//  2) screen14: bf16 16x16x32 MFMA GEMM, plain m97 sync, BK=64. Session
//     2x2 matrix: time invariant to instruction mix within an occupancy
//     tier (screen8 170 ~ screen13 174 @41%; screen11 201 ~ screen12 198
//     @22%) -> the cost is the SYNC SKELETON (~3.2k cyc/slice toll vs
//     ~1.1k real critical path; resource floors all ~2-4x below measured).
//     Fix: fewer, fatter slices. BK=64 as two verified BK=32 sub-slices
//     (disjoint sub-buffers; STAGE/COMPUTE byte-identical per sub-slice)
//     -> 16 iterations, 32 barriers/block (was 64). LDS 24KB+8.5KB -> 4
//     blocks/CU kept; VGPR ~56 -> 4 waves/SIMD kept. Block 64x128, wave
//     tile 32x64, 0.75 ds/MFMA. Epilogue: two-stage half-merge (stride-17
//     LDS). Candidate layout bit-identical to screen5..13. XCD swizzle:
//     XCD owns 8 windows -> 2 MB B L2-resident.
//  3) finalize6: 2 waves per row; 512 sorted-8 groups -> 6-level butterfly
//     bitonic keep-12 merge -> EXACT fp32 rescore with B fragments RETAINED
//     in registers -> top-8 by (d2, idx) -> w = 1/(sqrt(max(d2,1e-12))+0.1)
//     -> weighted sum from registers.
// Fallback (small ws): round-1 pure-fp32 path (verified correct).

typedef short bf16x8 __attribute__((ext_vector_type(8)));
typedef float f32x4 __attribute__((ext_vector_type(4)));

#define SENTINEL 1e30f
#define BKK 32

static __device__ __forceinline__ unsigned short f2bf(float f) {
  unsigned u = __float_as_uint(f);
  return (unsigned short)((u + 0x7fffu + ((u >> 16) & 1u)) >> 16);
}

// ---------------- fast path kernels ----------------
// grid: N + M blocks. bid < N: convert A row. else: convert B row + norm.
__global__ __launch_bounds__(256) void convert_all_kernel(
    const float* __restrict__ A, const float* __restrict__ B,
    unsigned short* __restrict__ Abf, unsigned short* __restrict__ Bbf,
    float* __restrict__ y2, int N) {
  const int bid = blockIdx.x;
  const int tid = threadIdx.x;
  if (bid < N) {
    const float4 v = ((const float4*)&A[(size_t)bid * 1024])[tid];
    ushort4 o;
    o.x = f2bf(v.x); o.y = f2bf(v.y); o.z = f2bf(v.z); o.w = f2bf(v.w);
    ((ushort4*)&Abf[(size_t)bid * 1024])[tid] = o;
  } else {
    const int m = bid - N;
    __shared__ float red[256];
    const float4 v = ((const float4*)&B[(size_t)m * 1024])[tid];
    ushort4 o;
    o.x = f2bf(v.x); o.y = f2bf(v.y); o.z = f2bf(v.z); o.w = f2bf(v.w);
    ((ushort4*)&Bbf[(size_t)m * 1024])[tid] = o;
    red[tid] = v.x * v.x + v.y * v.y + v.z * v.z + v.w * v.w;
    __syncthreads();
    for (int s = 128; s > 0; s >>= 1) {
      if (tid < s) red[tid] += red[tid + s];
      __syncthreads();
    }
    if (tid == 0) y2[m] = red[0];
  }
}

// ascending compare-exchange on (s, i) register pairs
#define CAS(sa, ia, sb, ib)                         \
  do {                                              \
    if ((sa) > (sb)) {                              \
      const float _t = (sa); (sa) = (sb); (sb) = _t;\
      const int _u = (ia); (ia) = (ib); (ib) = _u;  \
    }                                               \
  } while (0)

// stage k-slice sk (k0 = sk*32) into LDS sub-buffer `sub`.
// Wave w stages A rows [w*16,w*16+16) (1 glds) and B rows [w*32,w*32+32)
// (2 glds): 3 glds per wave per sub-slice.
#define STAGE(sk, sub)                                                        \
  do {                                                                        \
    const unsigned short* gA_ =                                               \
        Abf + (size_t)(r0 + w * 16 + srow) * 1024 + (sk) * 32 + sofs;         \
    const unsigned short* gB_ =                                               \
        Bbf + (size_t)(c0 + w * 32 + srow) * 1024 + (sk) * 32 + sofs;         \
    __builtin_amdgcn_global_load_lds(                                         \
        (const __attribute__((address_space(1))) void*)gA_,                   \
        (__attribute__((address_space(3))) void*)&As[sub][(w * 16) * 32],     \
        16, 0, 0);                                                            \
    __builtin_amdgcn_global_load_lds(                                         \
        (const __attribute__((address_space(1))) void*)gB_,                   \
        (__attribute__((address_space(3))) void*)&Bs[sub][(w * 32) * 32],     \
        16, 0, 0);                                                            \
    __builtin_amdgcn_global_load_lds(                                         \
        (const __attribute__((address_space(1))) void*)(gB_ + (size_t)16 * 1024), \
        (__attribute__((address_space(3))) void*)&Bs[sub][(w * 32 + 16) * 32],\
        16, 0, 0);                                                            \
  } while (0)

// 6 ds_read_b128 feed 8 MFMA16 (wave tile 32x64) per sub-slice.
#define COMPUTE(sub)                                                          \
  do {                                                                        \
    bf16x8 af[2], bfr[4];                                                     \
    _Pragma("unroll")                                                         \
    for (int fi = 0; fi < 2; ++fi)                                            \
      af[fi] = *(const bf16x8*)&As[sub][(frowA + fi * 16) * 32 + fofs];       \
    _Pragma("unroll")                                                         \
    for (int fj = 0; fj < 4; ++fj)                                            \
      bfr[fj] = *(const bf16x8*)&Bs[sub][(frowB + fj * 16) * 32 + fofs];      \
    __builtin_amdgcn_s_setprio(1);                                            \
    _Pragma("unroll")                                                         \
    for (int fi = 0; fi < 2; ++fi)                                            \
      _Pragma("unroll")                                                       \
      for (int fj = 0; fj < 4; ++fj)                                          \
        acc[fi][fj] = __builtin_amdgcn_mfma_f32_16x16x32_bf16(                \
            bfr[fj], af[fi], acc[fi][fj], 0, 0, 0);                           \
    __builtin_amdgcn_s_setprio(0);                                            \
  } while (0)

// grid: (64, N/64) blocks x 256 threads (4 blocks/CU, 16 waves/CU).
// blockIdx.x -> xcd = bx&7; window = xcd*8 + ((bx>>3)&7) [XCD owns 8
// windows = 1024 B-cols = 2 MB L2-resident]; rowtile = blockIdx.y.
// Block tile 64 rows x 128 cols; wave (wr,wc) owns rows [wr*32,+32) x cols
// [wc*64,+64) via 2x4 16x16 MFMA tiles. K-loop: BK=64 = two BK=32
// sub-slices per barrier pair -> 16 iterations, 32 barriers/block.
// Epilogue: per-row top-8 of each 64-col half -> LDS (stride-17 pad) ->
// 64-thread merge of halves -> sorted top-8 per row per 128-col window.
__global__ __launch_bounds__(256) void screen14_kernel(
    const unsigned short* __restrict__ Abf, const unsigned short* __restrict__ Bbf,
    const float* __restrict__ y2g,
    float* __restrict__ cand_s, int* __restrict__ cand_i) {
  __shared__ unsigned short As[2][64 * 32];   // 8 KB
  __shared__ unsigned short Bs[2][128 * 32];  // 16 KB
  __shared__ float mrg_s[64 * 17];            // 4.25 KB (stride-17 pad)
  __shared__ int mrg_i[64 * 17];              // 4.25 KB

  const int tid = threadIdx.x;
  const int w = tid >> 6;        // 0..3
  const int lane = tid & 63;
  const int wr = w >> 1;         // row half (32 rows)
  const int wc = w & 1;          // col half (64 cols)

  const int bx = blockIdx.x;                        // 0..63
  const int window = (bx & 7) * 8 + ((bx >> 3) & 7);  // 0..63
  const int r0 = blockIdx.y * 64;
  const int c0 = window * 128;

  // staging: lane -> LDS slot (16 rows per glds), swizzle on global source
  const int srow = lane >> 2;                          // 0..15
  const int sofs = ((lane & 3) ^ ((lane >> 3) & 3)) * 8;

  // fragment reads: LDS col = kc ^ ((row>>1)&3), kc = lane>>4 (verified
  // 0-conflict pattern from screen6/8/10/11/12/13)
  const int frowA = wr * 32 + (lane & 15);
  const int frowB = wc * 64 + (lane & 15);
  const int fofs = ((lane >> 4) ^ ((lane >> 1) & 3)) * 8;
  const int cgrp = (lane >> 4) * 4;

  f32x4 acc[2][4];
#pragma unroll
  for (int fi = 0; fi < 2; ++fi)
#pragma unroll
    for (int fj = 0; fj < 4; ++fj) {
      f32x4 z = {0.f, 0.f, 0.f, 0.f};
      acc[fi][fj] = z;
    }

  // BK=64 skeleton: 16 iterations, 2 barriers each (was 32 x 2).
#pragma unroll 1
  for (int t = 0; t < 16; ++t) {
    __syncthreads();   // previous COMPUTEs' LDS reads complete
    STAGE(2 * t, 0);
    STAGE(2 * t + 1, 1);
    __syncthreads();   // both sub-slices staged & visible
    COMPUTE(0);
    COMPUTE(1);
  }

  // epilogue stage 1: per fi, per-lane top-8 of 16 scores, then merge the
  // 4 lanes sharing a row -> lanes 0..15 hold the row's 64-col-half top-8.
#pragma unroll
  for (int fi = 0; fi < 2; ++fi) {
    float ls[8];
    int li[8];
#pragma unroll
    for (int j = 0; j < 8; ++j) { ls[j] = SENTINEL; li[j] = 0x7fffffff; }
    const int cb = c0 + wc * 64 + cgrp;
#pragma unroll
    for (int fj = 0; fj < 4; ++fj) {
      const float4 y2q = *(const float4*)&y2g[c0 + wc * 64 + fj * 16 + cgrp];
#pragma unroll
      for (int reg = 0; reg < 4; ++reg) {
        const float s = y2q[reg] - 2.0f * acc[fi][fj][reg];
        if (s < ls[7]) {
          ls[7] = s; li[7] = cb + fj * 16 + reg;
#pragma unroll
          for (int j = 7; j > 0; --j) {
            if (ls[j] < ls[j - 1]) {
              const float tt = ls[j]; ls[j] = ls[j - 1]; ls[j - 1] = tt;
              const int u2 = li[j]; li[j] = li[j - 1]; li[j - 1] = u2;
            }
          }
        }
      }
    }
    // merge sorted 8-lists across the 4 lanes sharing this row
#pragma unroll
    for (int off = 16; off <= 32; off <<= 1) {
      float rs[8];
      int ri[8];
#pragma unroll
      for (int j = 0; j < 8; ++j) {
        rs[j] = __shfl_xor(ls[j], off, 64);
        ri[j] = __shfl_xor(li[j], off, 64);
      }
      float ms[8];
      int mi_[8];
#pragma unroll
      for (int i = 0; i < 8; ++i) {
        const bool tk = ls[i] < rs[7 - i];
        ms[i] = tk ? ls[i] : rs[7 - i];
        mi_[i] = tk ? li[i] : ri[7 - i];
      }
      CAS(ms[0], mi_[0], ms[4], mi_[4]);
      CAS(ms[1], mi_[1], ms[5], mi_[5]);
      CAS(ms[2], mi_[2], ms[6], mi_[6]);
      CAS(ms[3], mi_[3], ms[7], mi_[7]);
      CAS(ms[0], mi_[0], ms[2], mi_[2]);
      CAS(ms[1], mi_[1], ms[3], mi_[3]);
      CAS(ms[4], mi_[4], ms[6], mi_[6]);
      CAS(ms[5], mi_[5], ms[7], mi_[7]);
      CAS(ms[0], mi_[0], ms[1], mi_[1]);
      CAS(ms[2], mi_[2], ms[3], mi_[3]);
      CAS(ms[4], mi_[4], ms[5], mi_[5]);
      CAS(ms[6], mi_[6], ms[7], mi_[7]);
#pragma unroll
      for (int j = 0; j < 8; ++j) { ls[j] = ms[j]; li[j] = mi_[j]; }
    }
    if ((lane >> 4) == 0) {  // lanes 0..15: row half-window top-8 -> LDS
      const int rl = wr * 32 + fi * 16 + lane;
#pragma unroll
      for (int j = 0; j < 8; ++j) {
        mrg_s[rl * 17 + wc * 8 + j] = ls[j];
        mrg_i[rl * 17 + wc * 8 + j] = li[j];
      }
    }
  }
  __syncthreads();

  // epilogue stage 2: 64 threads merge the two sorted halves per row.
  if (tid < 64) {
    const int rl = tid;
    float a8[8], b8[8];
    int ai[8], bi8[8];
#pragma unroll
    for (int j = 0; j < 8; ++j) {
      a8[j] = mrg_s[rl * 17 + j];
      ai[j] = mrg_i[rl * 17 + j];
      b8[j] = mrg_s[rl * 17 + 8 + j];
      bi8[j] = mrg_i[rl * 17 + 8 + j];
    }
    float ms[8];
    int mi_[8];
#pragma unroll
    for (int i = 0; i < 8; ++i) {
      const bool tk = a8[i] < b8[7 - i];
      ms[i] = tk ? a8[i] : b8[7 - i];
      mi_[i] = tk ? ai[i] : bi8[7 - i];
    }
    CAS(ms[0], mi_[0], ms[4], mi_[4]);
    CAS(ms[1], mi_[1], ms[5], mi_[5]);
    CAS(ms[2], mi_[2], ms[6], mi_[6]);
    CAS(ms[3], mi_[3], ms[7], mi_[7]);
    CAS(ms[0], mi_[0], ms[2], mi_[2]);
    CAS(ms[1], mi_[1], ms[3], mi_[3]);
    CAS(ms[4], mi_[4], ms[6], mi_[6]);
    CAS(ms[5], mi_[5], ms[7], mi_[7]);
    CAS(ms[0], mi_[0], ms[1], mi_[1]);
    CAS(ms[2], mi_[2], ms[3], mi_[3]);
    CAS(ms[4], mi_[4], ms[5], mi_[5]);
    CAS(ms[6], mi_[6], ms[7], mi_[7]);
    const int row = r0 + rl;
    const size_t base = ((size_t)row * 64 + window) * 8;
#pragma unroll
    for (int j = 0; j < 8; ++j) {
      cand_s[base + j] = ms[j];
      cand_i[base + j] = mi_[j];
    }
  }
}

// 2 waves per row: grid N/2 blocks x 256 threads (4 waves = 2 rows x 2
// wave-halves). Lane loads sorted group `lane` (8 contiguous cands) ->
// 6-level butterfly bitonic keep-12 merge -> exact fp32 rescore with B
// fragments kept in registers -> top-8 -> weighted sum from registers.
__global__ __launch_bounds__(256) void finalize6_kernel(
    const float* __restrict__ A, const float* __restrict__ B,
    const float* __restrict__ y2g,
    const float* __restrict__ cand_s, const int* __restrict__ cand_i,
    float* __restrict__ out) {
  const int tid = threadIdx.x;
  const int w = tid >> 6;
  const int lane = tid & 63;
  const int rloc = w >> 1;  // row within block
  const int wh = w & 1;     // wave-half along D
  const int n = blockIdx.x * 2 + rloc;
  __shared__ float comb[2][2][16];

  float s12[12];
  int i12[12];
  {
    const float4* cs = (const float4*)&cand_s[(size_t)n * 512 + lane * 8];
    const int4* cj = (const int4*)&cand_i[(size_t)n * 512 + lane * 8];
    const float4 sa = cs[0], sb = cs[1];
    const int4 ja = cj[0], jb = cj[1];
    s12[0] = sa.x; s12[1] = sa.y; s12[2] = sa.z; s12[3] = sa.w;
    s12[4] = sb.x; s12[5] = sb.y; s12[6] = sb.z; s12[7] = sb.w;
    i12[0] = ja.x; i12[1] = ja.y; i12[2] = ja.z; i12[3] = ja.w;
    i12[4] = jb.x; i12[5] = jb.y; i12[6] = jb.z; i12[7] = jb.w;
#pragma unroll
    for (int j = 8; j < 12; ++j) { s12[j] = SENTINEL; i12[j] = 0x7fffffff; }
  }

  // butterfly merge: sorted-12 + sorted-12 -> lowest-12 sorted.
#pragma unroll
  for (int off = 1; off <= 32; off <<= 1) {
    float rs[12];
    int ri[12];
#pragma unroll
    for (int j = 0; j < 12; ++j) {
      rs[j] = __shfl_xor(s12[j], off, 64);
      ri[j] = __shfl_xor(i12[j], off, 64);
    }
    float ms[12];
    int mj[12];
#pragma unroll
    for (int j = 0; j < 12; ++j) {
      const bool tke = s12[j] < rs[11 - j];
      ms[j] = tke ? s12[j] : rs[11 - j];
      mj[j] = tke ? i12[j] : ri[11 - j];
    }
    CAS(ms[0], mj[0], ms[8], mj[8]);  CAS(ms[1], mj[1], ms[9], mj[9]);
    CAS(ms[2], mj[2], ms[10], mj[10]); CAS(ms[3], mj[3], ms[11], mj[11]);
    CAS(ms[4], mj[4], ms[8], mj[8]);  CAS(ms[5], mj[5], ms[9], mj[9]);
    CAS(ms[6], mj[6], ms[10], mj[10]); CAS(ms[7], mj[7], ms[11], mj[11]);
    CAS(ms[0], mj[0], ms[2], mj[2]);  CAS(ms[1], mj[1], ms[3], mj[3]);
    CAS(ms[4], mj[4], ms[6], mj[6]);  CAS(ms[5], mj[5], ms[7], mj[7]);
    CAS(ms[8], mj[8], ms[10], mj[10]); CAS(ms[9], mj[9], ms[11], mj[11]);
    CAS(ms[0], mj[0], ms[1], mj[1]);  CAS(ms[2], mj[2], ms[3], mj[3]);
    CAS(ms[4], mj[4], ms[5], mj[5]);  CAS(ms[6], mj[6], ms[7], mj[7]);
    CAS(ms[8], mj[8], ms[9], mj[9]);  CAS(ms[10], mj[10], ms[11], mj[11]);
#pragma unroll
    for (int j = 0; j < 12; ++j) { s12[j] = ms[j]; i12[j] = mj[j]; }
  }
  // i12[0..11]: approx top-12 indices, identical in every lane/wave.

  // exact fp32 partial dots; B fragments RETAINED for the output sum.
  const float4* Arow = (const float4*)&A[(size_t)n * 1024];
  const int fbase = wh * 128 + lane * 2;
  float4 a4[2];
  a4[0] = Arow[fbase];
  a4[1] = Arow[fbase + 1];
  float4 bk0[12], bk1[12];
#pragma unroll
  for (int j = 0; j < 12; ++j) {
    const float4* Brow = (const float4*)&B[(size_t)i12[j] * 1024];
    bk0[j] = Brow[fbase];
    bk1[j] = Brow[fbase + 1];
  }
  float part[13];
  part[12] = a4[0].x * a4[0].x + a4[0].y * a4[0].y + a4[0].z * a4[0].z +
             a4[0].w * a4[0].w + a4[1].x * a4[1].x + a4[1].y * a4[1].y +
             a4[1].z * a4[1].z + a4[1].w * a4[1].w;
#pragma unroll
  for (int j = 0; j < 12; ++j) {
    part[j] = a4[0].x * bk0[j].x + a4[0].y * bk0[j].y + a4[0].z * bk0[j].z +
              a4[0].w * bk0[j].w;
    part[j] += a4[1].x * bk1[j].x + a4[1].y * bk1[j].y + a4[1].z * bk1[j].z +
               a4[1].w * bk1[j].w;
  }
#pragma unroll
  for (int r = 0; r < 13; ++r) {
#pragma unroll
    for (int off = 32; off >= 1; off >>= 1) part[r] += __shfl_xor(part[r], off, 64);
  }
  if (lane == 0) {
#pragma unroll
    for (int r = 0; r < 13; ++r) comb[rloc][wh][r] = part[r];
  }
  __syncthreads();
  float tot[13];
#pragma unroll
  for (int r = 0; r < 13; ++r) tot[r] = comb[rloc][0][r] + comb[rloc][1][r];

  // uniform redundant selection: top-8 by (d2, idx); weights land in wsel[]
  const float x2 = tot[12];
  float d2v[12];
  float wsel[12];
  bool used[12];
#pragma unroll
  for (int j = 0; j < 12; ++j) {
    d2v[j] = x2 + y2g[i12[j]] - 2.0f * tot[j];
    used[j] = false;
    wsel[j] = 0.0f;
  }
  float wsum = 0.0f;
  for (int k = 0; k < 8; ++k) {
    float bd = SENTINEL;
    int bi = 0x7fffffff, bslot = 0;
#pragma unroll
    for (int j = 0; j < 12; ++j) {
      if (used[j]) continue;
      const float d2 = d2v[j];
      if (d2 < bd || (d2 == bd && i12[j] < bi)) { bd = d2; bi = i12[j]; bslot = j; }
    }
    used[bslot] = true;
    const float d2c = fmaxf(bd, 1e-12f);
    const float wv = 1.0f / (sqrtf(d2c) + 0.1f);
    wsel[bslot] = wv;
    wsum += wv;
  }
  const float inv = 1.0f / wsum;

  float4 o0 = {0, 0, 0, 0}, o1 = {0, 0, 0, 0};
#pragma unroll
  for (int j = 0; j < 12; ++j) {
    const float wv = wsel[j];
    o0.x += wv * bk0[j].x; o0.y += wv * bk0[j].y;
    o0.z += wv * bk0[j].z; o0.w += wv * bk0[j].w;
    o1.x += wv * bk1[j].x; o1.y += wv * bk1[j].y;
    o1.z += wv * bk1[j].z; o1.w += wv * bk1[j].w;
  }
  o0.x *= inv; o0.y *= inv; o0.z *= inv; o0.w *= inv;
  o1.x *= inv; o1.y *= inv; o1.z *= inv; o1.w *= inv;
  float4* Orow = (float4*)&out[(size_t)n * 1024];
  Orow[fbase] = o0;
  Orow[fbase + 1] = o1;
}

// ---------------- fallback path (round-1, verified) ----------------
__global__ __launch_bounds__(256) void rownorm_kernel(
    const float* __restrict__ B, float* __restrict__ y2) {
  const int m = blockIdx.x;
  const int tid = threadIdx.x;
  __shared__ float red[256];
  const float4 v = *(const float4*)&B[(size_t)m * 1024 + tid * 4];
  red[tid] = v.x * v.x + v.y * v.y + v.z * v.z + v.w * v.w;
  __syncthreads();
  for (int s = 128; s > 0; s >>= 1) {
    if (tid < s) red[tid] += red[tid + s];
    __syncthreads();
  }
  if (tid == 0) y2[m] = red[0];
}

__global__ __launch_bounds__(256) void knn_chunk_kernel(
    const float* __restrict__ A, const float* __restrict__ B,
    const float* __restrict__ y2g,
    float* __restrict__ cand_s, int* __restrict__ cand_i) {
  __shared__ float As[BKK][68];
  __shared__ float Bs[BKK][68];
  __shared__ float Sc[64][65];

  const int tid = threadIdx.x;
  const int tx = tid & 15;
  const int ty = tid >> 4;
  const int r0 = blockIdx.y * 64;
  const int c0 = blockIdx.x * 1024;
  const int lrow = tid >> 3;
  const int lk = (tid & 7) * 4;

  float top_s[8];
  int top_i[8];
#pragma unroll
  for (int j = 0; j < 8; ++j) { top_s[j] = SENTINEL; top_i[j] = 0x7fffffff; }

  for (int tile = 0; tile < 16; ++tile) {
    const int cbase = c0 + tile * 64;
    float acc[4][4];
#pragma unroll
    for (int i = 0; i < 4; ++i)
#pragma unroll
      for (int j = 0; j < 4; ++j) acc[i][j] = 0.0f;

    for (int k0 = 0; k0 < 1024; k0 += BKK) {
      const float4 a0 = *(const float4*)&A[(size_t)(r0 + lrow) * 1024 + k0 + lk];
      const float4 a1 = *(const float4*)&A[(size_t)(r0 + lrow + 32) * 1024 + k0 + lk];
      const float4 b0 = *(const float4*)&B[(size_t)(cbase + lrow) * 1024 + k0 + lk];
      const float4 b1 = *(const float4*)&B[(size_t)(cbase + lrow + 32) * 1024 + k0 + lk];
      __syncthreads();
      As[lk + 0][lrow] = a0.x; As[lk + 1][lrow] = a0.y;
      As[lk + 2][lrow] = a0.z; As[lk + 3][lrow] = a0.w;
      As[lk + 0][lrow + 32] = a1.x; As[lk + 1][lrow + 32] = a1.y;
      As[lk + 2][lrow + 32] = a1.z; As[lk + 3][lrow + 32] = a1.w;
      Bs[lk + 0][lrow] = b0.x; Bs[lk + 1][lrow] = b0.y;
      Bs[lk + 2][lrow] = b0.z; Bs[lk + 3][lrow] = b0.w;
      Bs[lk + 0][lrow + 32] = b1.x; Bs[lk + 1][lrow + 32] = b1.y;
      Bs[lk + 2][lrow + 32] = b1.z; Bs[lk + 3][lrow + 32] = b1.w;
      __syncthreads();
#pragma unroll
      for (int kk = 0; kk < BKK; ++kk) {
        const float4 av = *(const float4*)&As[kk][ty * 4];
        const float4 bv = *(const float4*)&Bs[kk][tx * 4];
        acc[0][0] += av.x * bv.x; acc[0][1] += av.x * bv.y;
        acc[0][2] += av.x * bv.z; acc[0][3] += av.x * bv.w;
        acc[1][0] += av.y * bv.x; acc[1][1] += av.y * bv.y;
        acc[1][2] += av.y * bv.z; acc[1][3] += av.y * bv.w;
        acc[2][0] += av.z * bv.x; acc[2][1] += av.z * bv.y;
        acc[2][2] += av.z * bv.z; acc[2][3] += av.z * bv.w;
        acc[3][0] += av.w * bv.x; acc[3][1] += av.w * bv.y;
        acc[3][2] += av.w * bv.z; acc[3][3] += av.w * bv.w;
      }
    }
#pragma unroll
    for (int i = 0; i < 4; ++i) {
      const int row = ty * 4 + i;
#pragma unroll
      for (int j = 0; j < 4; ++j) {
        const int col = tx * 4 + j;
        Sc[row][col] = y2g[cbase + col] - 2.0f * acc[i][j];
      }
    }
    __syncthreads();
    if (tid < 64) {
      for (int c = 0; c < 64; ++c) {
        const float s = Sc[tid][c];
        if (s < top_s[7]) {
          top_s[7] = s; top_i[7] = cbase + c;
#pragma unroll
          for (int j = 7; j > 0; --j) {
            if (top_s[j] < top_s[j - 1]) {
              const float tss = top_s[j]; top_s[j] = top_s[j - 1]; top_s[j - 1] = tss;
              const int tii = top_i[j]; top_i[j] = top_i[j - 1]; top_i[j - 1] = tii;
            }
          }
        }
      }
    }
  }

  if (tid < 64) {
    const int n = r0 + tid;
    const int base = (n * gridDim.x + blockIdx.x) * 8;
#pragma unroll
    for (int j = 0; j < 8; ++j) {
      cand_s[base + j] = top_s[j];
      cand_i[base + j] = top_i[j];
    }
  }
}

__global__ __launch_bounds__(256) void finalize_kernel(
    const float* __restrict__ A, const float* __restrict__ B,
    const float* __restrict__ cand_s, const int* __restrict__ cand_i,
    float* __restrict__ out, int nchunks) {
  const int n = blockIdx.x;
  const int tid = threadIdx.x;
  __shared__ float red[256];
  __shared__ float ls[64];
  __shared__ int li[64];
  __shared__ float wsh2[8];
  __shared__ int wid[8];
  __shared__ float wsum_sh;

  const int ncand = nchunks * 8;
  const float4 a = *(const float4*)&A[(size_t)n * 1024 + tid * 4];
  red[tid] = a.x * a.x + a.y * a.y + a.z * a.z + a.w * a.w;
  if (tid < ncand) {
    ls[tid] = cand_s[n * ncand + tid];
    li[tid] = cand_i[n * ncand + tid];
  }
  __syncthreads();
  for (int s = 128; s > 0; s >>= 1) {
    if (tid < s) red[tid] += red[tid + s];
    __syncthreads();
  }
  if (tid == 0) {
    const float x2 = red[0];
    float wsum = 0.0f;
    for (int j = 0; j < 8; ++j) {
      float bs = SENTINEL;
      int bi = 0x7fffffff;
      int bp = 0;
      for (int c = 0; c < ncand; ++c) {
        const float s_ = ls[c];
        const int i_ = li[c];
        if (s_ < bs || (s_ == bs && i_ < bi)) { bs = s_; bi = i_; bp = c; }
      }
      ls[bp] = SENTINEL; li[bp] = 0x7fffffff;
      float d2 = x2 + bs;
      d2 = fmaxf(d2, 1e-12f);
      const float wkk = 1.0f / (sqrtf(d2) + 0.1f);
      wsh2[j] = wkk; wid[j] = bi;
      wsum += wkk;
    }
    wsum_sh = wsum;
  }
  __syncthreads();
  const float inv = 1.0f / wsum_sh;
  float ox = 0.0f, oy = 0.0f, oz = 0.0f, ow = 0.0f;
#pragma unroll
  for (int j = 0; j < 8; ++j) {
    const float wkk = wsh2[j];
    const float4 v = *(const float4*)&B[(size_t)wid[j] * 1024 + tid * 4];
    ox += wkk * v.x; oy += wkk * v.y; oz += wkk * v.z; ow += wkk * v.w;
  }
  float4 o;
  o.x = ox * inv; o.y = oy * inv; o.z = oz * inv; o.w = ow * inv;
  *(float4*)&out[(size_t)n * 1024 + tid * 4] = o;
}

extern "C" void kernel_launch(void* const* d_in, const int* in_sizes, int n_in,
                              void* d_out, int out_size, void* d_ws, size_t ws_size,
                              hipStream_t stream) {
  const float* A = (const float*)d_in[0];
  const float* Bm = (const float*)d_in[1];
  const int D = 1024;
  const int N = in_sizes[0] / D;  // 4096
  const int M = in_sizes[1] / D;  // 8192

  const size_t needA = (size_t)N * D * 2;
  const size_t needB = (size_t)M * D * 2;
  const size_t needC = (size_t)N * 512 * 4;  // cand_s (== cand_i)
  const size_t need = needA + needB + (size_t)M * 4 + 2 * needC;

  if (ws_size >= need && M == 8192 && N % 64 == 0 && N % 2 == 0) {
    unsigned short* Abf = (unsigned short*)d_ws;
    unsigned short* Bbf = Abf + (size_t)N * D;
    float* y2 = (float*)(Bbf + (size_t)M * D);
    float* cand_s = y2 + M;
    int* cand_i = (int*)(cand_s + (size_t)N * 512);

    convert_all_kernel<<<N + M, 256, 0, stream>>>(A, Bm, Abf, Bbf, y2, N);
    dim3 g(64, N / 64);
    screen14_kernel<<<g, 256, 0, stream>>>(Abf, Bbf, y2, cand_s, cand_i);
    finalize6_kernel<<<N / 2, 256, 0, stream>>>(A, Bm, y2, cand_s, cand_i,
                                                (float*)d_out);
  } else {
    float* y2 = (float*)d_ws;
    float* cand_s = y2 + M;
    int* cand_i = (int*)(cand_s + (size_t)N * 64);
    rownorm_kernel<<<M, 256, 0, stream>>>(Bm, y2);
    dim3 gridB(M / 1024, N / 64);
    knn_chunk_kernel<<<gridB, 256, 0, stream>>>(A, Bm, y2, cand_s, cand_i);
    finalize_kernel<<<N, 256, 0, stream>>>(A, Bm, cand_s, cand_i, (float*)d_out, M / 1024);
  }
}

// Round 12
// 278.351 us; speedup vs baseline: 1.4277x; 1.1074x over previous
//
#include <hip/hip_runtime.h>

// KNN (K=8) + inverse-distance-weighted average, MFMA screening version.
// data1: [N=4096, D=1024] fp32, data2: [M=8192, D=1024] fp32, out: [N, D] fp32.
//
// Fast path:
//  1) convert_all: A -> bf16; B -> bf16 fused with y2[m]=||B[m]||^2
//  2) screen14: bf16 16x16x32 MFMA GEMM, plain m97 sync, BK=64 (R11: 161us,
//     best; barrier-skeleton halving -13us). Block 64x128, 4 waves, wave
//     tile 32x64, 0.75 ds/MFMA, 4 blocks/CU / 16 waves/CU, 0 conflicts.
//     XCD swizzle: XCD owns 8 windows -> 2 MB B L2-resident.
//  3) finalize7: finalize6 with SCRATCH-FREE selection. Rule-#20 bug in all
//     prior finalizes: `used[bslot]=true; wsel[bslot]=wv` with runtime bslot
//     forced used[]/wsel[] into scratch (local memory) -> ~130 global-backed
//     scratch accesses per thread in a serial loop (~90us hidden cost;
//     explains why R1/R3 finalize rewrites were null). Fix: usedmask bitmask
//     in a register + predicated unrolled register writes for wsel. Selection
//     order, tie-breaks, weights bit-identical.
// Fallback (small ws): round-1 pure-fp32 path (verified correct).

typedef short bf16x8 __attribute__((ext_vector_type(8)));
typedef float f32x4 __attribute__((ext_vector_type(4)));

#define SENTINEL 1e30f
#define BKK 32

static __device__ __forceinline__ unsigned short f2bf(float f) {
  unsigned u = __float_as_uint(f);
  return (unsigned short)((u + 0x7fffu + ((u >> 16) & 1u)) >> 16);
}

// ---------------- fast path kernels ----------------
// grid: N + M blocks. bid < N: convert A row. else: convert B row + norm.
__global__ __launch_bounds__(256) void convert_all_kernel(
    const float* __restrict__ A, const float* __restrict__ B,
    unsigned short* __restrict__ Abf, unsigned short* __restrict__ Bbf,
    float* __restrict__ y2, int N) {
  const int bid = blockIdx.x;
  const int tid = threadIdx.x;
  if (bid < N) {
    const float4 v = ((const float4*)&A[(size_t)bid * 1024])[tid];
    ushort4 o;
    o.x = f2bf(v.x); o.y = f2bf(v.y); o.z = f2bf(v.z); o.w = f2bf(v.w);
    ((ushort4*)&Abf[(size_t)bid * 1024])[tid] = o;
  } else {
    const int m = bid - N;
    __shared__ float red[256];
    const float4 v = ((const float4*)&B[(size_t)m * 1024])[tid];
    ushort4 o;
    o.x = f2bf(v.x); o.y = f2bf(v.y); o.z = f2bf(v.z); o.w = f2bf(v.w);
    ((ushort4*)&Bbf[(size_t)m * 1024])[tid] = o;
    red[tid] = v.x * v.x + v.y * v.y + v.z * v.z + v.w * v.w;
    __syncthreads();
    for (int s = 128; s > 0; s >>= 1) {
      if (tid < s) red[tid] += red[tid + s];
      __syncthreads();
    }
    if (tid == 0) y2[m] = red[0];
  }
}

// ascending compare-exchange on (s, i) register pairs
#define CAS(sa, ia, sb, ib)                         \
  do {                                              \
    if ((sa) > (sb)) {                              \
      const float _t = (sa); (sa) = (sb); (sb) = _t;\
      const int _u = (ia); (ia) = (ib); (ib) = _u;  \
    }                                               \
  } while (0)

// stage k-slice sk (k0 = sk*32) into LDS sub-buffer `sub`.
// Wave w stages A rows [w*16,w*16+16) (1 glds) and B rows [w*32,w*32+32)
// (2 glds): 3 glds per wave per sub-slice.
#define STAGE(sk, sub)                                                        \
  do {                                                                        \
    const unsigned short* gA_ =                                               \
        Abf + (size_t)(r0 + w * 16 + srow) * 1024 + (sk) * 32 + sofs;         \
    const unsigned short* gB_ =                                               \
        Bbf + (size_t)(c0 + w * 32 + srow) * 1024 + (sk) * 32 + sofs;         \
    __builtin_amdgcn_global_load_lds(                                         \
        (const __attribute__((address_space(1))) void*)gA_,                   \
        (__attribute__((address_space(3))) void*)&As[sub][(w * 16) * 32],     \
        16, 0, 0);                                                            \
    __builtin_amdgcn_global_load_lds(                                         \
        (const __attribute__((address_space(1))) void*)gB_,                   \
        (__attribute__((address_space(3))) void*)&Bs[sub][(w * 32) * 32],     \
        16, 0, 0);                                                            \
    __builtin_amdgcn_global_load_lds(                                         \
        (const __attribute__((address_space(1))) void*)(gB_ + (size_t)16 * 1024), \
        (__attribute__((address_space(3))) void*)&Bs[sub][(w * 32 + 16) * 32],\
        16, 0, 0);                                                            \
  } while (0)

// 6 ds_read_b128 feed 8 MFMA16 (wave tile 32x64) per sub-slice.
#define COMPUTE(sub)                                                          \
  do {                                                                        \
    bf16x8 af[2], bfr[4];                                                     \
    _Pragma("unroll")                                                         \
    for (int fi = 0; fi < 2; ++fi)                                            \
      af[fi] = *(const bf16x8*)&As[sub][(frowA + fi * 16) * 32 + fofs];       \
    _Pragma("unroll")                                                         \
    for (int fj = 0; fj < 4; ++fj)                                            \
      bfr[fj] = *(const bf16x8*)&Bs[sub][(frowB + fj * 16) * 32 + fofs];      \
    __builtin_amdgcn_s_setprio(1);                                            \
    _Pragma("unroll")                                                         \
    for (int fi = 0; fi < 2; ++fi)                                            \
      _Pragma("unroll")                                                       \
      for (int fj = 0; fj < 4; ++fj)                                          \
        acc[fi][fj] = __builtin_amdgcn_mfma_f32_16x16x32_bf16(                \
            bfr[fj], af[fi], acc[fi][fj], 0, 0, 0);                           \
    __builtin_amdgcn_s_setprio(0);                                            \
  } while (0)

// grid: (64, N/64) blocks x 256 threads (4 blocks/CU, 16 waves/CU).
// blockIdx.x -> xcd = bx&7; window = xcd*8 + ((bx>>3)&7) [XCD owns 8
// windows = 1024 B-cols = 2 MB L2-resident]; rowtile = blockIdx.y.
// Block tile 64 rows x 128 cols; wave (wr,wc) owns rows [wr*32,+32) x cols
// [wc*64,+64) via 2x4 16x16 MFMA tiles. K-loop: BK=64 = two BK=32
// sub-slices per barrier pair -> 16 iterations, 32 barriers/block.
// Epilogue: per-row top-8 of each 64-col half -> LDS (stride-17 pad) ->
// 64-thread merge of halves -> sorted top-8 per row per 128-col window.
__global__ __launch_bounds__(256) void screen14_kernel(
    const unsigned short* __restrict__ Abf, const unsigned short* __restrict__ Bbf,
    const float* __restrict__ y2g,
    float* __restrict__ cand_s, int* __restrict__ cand_i) {
  __shared__ unsigned short As[2][64 * 32];   // 8 KB
  __shared__ unsigned short Bs[2][128 * 32];  // 16 KB
  __shared__ float mrg_s[64 * 17];            // 4.25 KB (stride-17 pad)
  __shared__ int mrg_i[64 * 17];              // 4.25 KB

  const int tid = threadIdx.x;
  const int w = tid >> 6;        // 0..3
  const int lane = tid & 63;
  const int wr = w >> 1;         // row half (32 rows)
  const int wc = w & 1;          // col half (64 cols)

  const int bx = blockIdx.x;                        // 0..63
  const int window = (bx & 7) * 8 + ((bx >> 3) & 7);  // 0..63
  const int r0 = blockIdx.y * 64;
  const int c0 = window * 128;

  // staging: lane -> LDS slot (16 rows per glds), swizzle on global source
  const int srow = lane >> 2;                          // 0..15
  const int sofs = ((lane & 3) ^ ((lane >> 3) & 3)) * 8;

  // fragment reads: LDS col = kc ^ ((row>>1)&3), kc = lane>>4 (verified
  // 0-conflict pattern from screen6/8/10/11/12/13)
  const int frowA = wr * 32 + (lane & 15);
  const int frowB = wc * 64 + (lane & 15);
  const int fofs = ((lane >> 4) ^ ((lane >> 1) & 3)) * 8;
  const int cgrp = (lane >> 4) * 4;

  f32x4 acc[2][4];
#pragma unroll
  for (int fi = 0; fi < 2; ++fi)
#pragma unroll
    for (int fj = 0; fj < 4; ++fj) {
      f32x4 z = {0.f, 0.f, 0.f, 0.f};
      acc[fi][fj] = z;
    }

  // BK=64 skeleton: 16 iterations, 2 barriers each.
#pragma unroll 1
  for (int t = 0; t < 16; ++t) {
    __syncthreads();   // previous COMPUTEs' LDS reads complete
    STAGE(2 * t, 0);
    STAGE(2 * t + 1, 1);
    __syncthreads();   // both sub-slices staged & visible
    COMPUTE(0);
    COMPUTE(1);
  }

  // epilogue stage 1: per fi, per-lane top-8 of 16 scores, then merge the
  // 4 lanes sharing a row -> lanes 0..15 hold the row's 64-col-half top-8.
#pragma unroll
  for (int fi = 0; fi < 2; ++fi) {
    float ls[8];
    int li[8];
#pragma unroll
    for (int j = 0; j < 8; ++j) { ls[j] = SENTINEL; li[j] = 0x7fffffff; }
    const int cb = c0 + wc * 64 + cgrp;
#pragma unroll
    for (int fj = 0; fj < 4; ++fj) {
      const float4 y2q = *(const float4*)&y2g[c0 + wc * 64 + fj * 16 + cgrp];
#pragma unroll
      for (int reg = 0; reg < 4; ++reg) {
        const float s = y2q[reg] - 2.0f * acc[fi][fj][reg];
        if (s < ls[7]) {
          ls[7] = s; li[7] = cb + fj * 16 + reg;
#pragma unroll
          for (int j = 7; j > 0; --j) {
            if (ls[j] < ls[j - 1]) {
              const float tt = ls[j]; ls[j] = ls[j - 1]; ls[j - 1] = tt;
              const int u2 = li[j]; li[j] = li[j - 1]; li[j - 1] = u2;
            }
          }
        }
      }
    }
    // merge sorted 8-lists across the 4 lanes sharing this row
#pragma unroll
    for (int off = 16; off <= 32; off <<= 1) {
      float rs[8];
      int ri[8];
#pragma unroll
      for (int j = 0; j < 8; ++j) {
        rs[j] = __shfl_xor(ls[j], off, 64);
        ri[j] = __shfl_xor(li[j], off, 64);
      }
      float ms[8];
      int mi_[8];
#pragma unroll
      for (int i = 0; i < 8; ++i) {
        const bool tk = ls[i] < rs[7 - i];
        ms[i] = tk ? ls[i] : rs[7 - i];
        mi_[i] = tk ? li[i] : ri[7 - i];
      }
      CAS(ms[0], mi_[0], ms[4], mi_[4]);
      CAS(ms[1], mi_[1], ms[5], mi_[5]);
      CAS(ms[2], mi_[2], ms[6], mi_[6]);
      CAS(ms[3], mi_[3], ms[7], mi_[7]);
      CAS(ms[0], mi_[0], ms[2], mi_[2]);
      CAS(ms[1], mi_[1], ms[3], mi_[3]);
      CAS(ms[4], mi_[4], ms[6], mi_[6]);
      CAS(ms[5], mi_[5], ms[7], mi_[7]);
      CAS(ms[0], mi_[0], ms[1], mi_[1]);
      CAS(ms[2], mi_[2], ms[3], mi_[3]);
      CAS(ms[4], mi_[4], ms[5], mi_[5]);
      CAS(ms[6], mi_[6], ms[7], mi_[7]);
#pragma unroll
      for (int j = 0; j < 8; ++j) { ls[j] = ms[j]; li[j] = mi_[j]; }
    }
    if ((lane >> 4) == 0) {  // lanes 0..15: row half-window top-8 -> LDS
      const int rl = wr * 32 + fi * 16 + lane;
#pragma unroll
      for (int j = 0; j < 8; ++j) {
        mrg_s[rl * 17 + wc * 8 + j] = ls[j];
        mrg_i[rl * 17 + wc * 8 + j] = li[j];
      }
    }
  }
  __syncthreads();

  // epilogue stage 2: 64 threads merge the two sorted halves per row.
  if (tid < 64) {
    const int rl = tid;
    float a8[8], b8[8];
    int ai[8], bi8[8];
#pragma unroll
    for (int j = 0; j < 8; ++j) {
      a8[j] = mrg_s[rl * 17 + j];
      ai[j] = mrg_i[rl * 17 + j];
      b8[j] = mrg_s[rl * 17 + 8 + j];
      bi8[j] = mrg_i[rl * 17 + 8 + j];
    }
    float ms[8];
    int mi_[8];
#pragma unroll
    for (int i = 0; i < 8; ++i) {
      const bool tk = a8[i] < b8[7 - i];
      ms[i] = tk ? a8[i] : b8[7 - i];
      mi_[i] = tk ? ai[i] : bi8[7 - i];
    }
    CAS(ms[0], mi_[0], ms[4], mi_[4]);
    CAS(ms[1], mi_[1], ms[5], mi_[5]);
    CAS(ms[2], mi_[2], ms[6], mi_[6]);
    CAS(ms[3], mi_[3], ms[7], mi_[7]);
    CAS(ms[0], mi_[0], ms[2], mi_[2]);
    CAS(ms[1], mi_[1], ms[3], mi_[3]);
    CAS(ms[4], mi_[4], ms[6], mi_[6]);
    CAS(ms[5], mi_[5], ms[7], mi_[7]);
    CAS(ms[0], mi_[0], ms[1], mi_[1]);
    CAS(ms[2], mi_[2], ms[3], mi_[3]);
    CAS(ms[4], mi_[4], ms[5], mi_[5]);
    CAS(ms[6], mi_[6], ms[7], mi_[7]);
    const int row = r0 + rl;
    const size_t base = ((size_t)row * 64 + window) * 8;
#pragma unroll
    for (int j = 0; j < 8; ++j) {
      cand_s[base + j] = ms[j];
      cand_i[base + j] = mi_[j];
    }
  }
}

// 2 waves per row: grid N/2 blocks x 256 threads (4 waves = 2 rows x 2
// wave-halves). Lane loads sorted group `lane` (8 contiguous cands) ->
// 6-level butterfly bitonic keep-12 merge -> exact fp32 rescore with B
// fragments kept in registers -> SCRATCH-FREE top-8 selection (bitmask +
// predicated register writes) -> weighted sum from registers.
__global__ __launch_bounds__(256) void finalize7_kernel(
    const float* __restrict__ A, const float* __restrict__ B,
    const float* __restrict__ y2g,
    const float* __restrict__ cand_s, const int* __restrict__ cand_i,
    float* __restrict__ out) {
  const int tid = threadIdx.x;
  const int w = tid >> 6;
  const int lane = tid & 63;
  const int rloc = w >> 1;  // row within block
  const int wh = w & 1;     // wave-half along D
  const int n = blockIdx.x * 2 + rloc;
  __shared__ float comb[2][2][16];

  float s12[12];
  int i12[12];
  {
    const float4* cs = (const float4*)&cand_s[(size_t)n * 512 + lane * 8];
    const int4* cj = (const int4*)&cand_i[(size_t)n * 512 + lane * 8];
    const float4 sa = cs[0], sb = cs[1];
    const int4 ja = cj[0], jb = cj[1];
    s12[0] = sa.x; s12[1] = sa.y; s12[2] = sa.z; s12[3] = sa.w;
    s12[4] = sb.x; s12[5] = sb.y; s12[6] = sb.z; s12[7] = sb.w;
    i12[0] = ja.x; i12[1] = ja.y; i12[2] = ja.z; i12[3] = ja.w;
    i12[4] = jb.x; i12[5] = jb.y; i12[6] = jb.z; i12[7] = jb.w;
#pragma unroll
    for (int j = 8; j < 12; ++j) { s12[j] = SENTINEL; i12[j] = 0x7fffffff; }
  }

  // butterfly merge: sorted-12 + sorted-12 -> lowest-12 sorted.
#pragma unroll
  for (int off = 1; off <= 32; off <<= 1) {
    float rs[12];
    int ri[12];
#pragma unroll
    for (int j = 0; j < 12; ++j) {
      rs[j] = __shfl_xor(s12[j], off, 64);
      ri[j] = __shfl_xor(i12[j], off, 64);
    }
    float ms[12];
    int mj[12];
#pragma unroll
    for (int j = 0; j < 12; ++j) {
      const bool tke = s12[j] < rs[11 - j];
      ms[j] = tke ? s12[j] : rs[11 - j];
      mj[j] = tke ? i12[j] : ri[11 - j];
    }
    CAS(ms[0], mj[0], ms[8], mj[8]);  CAS(ms[1], mj[1], ms[9], mj[9]);
    CAS(ms[2], mj[2], ms[10], mj[10]); CAS(ms[3], mj[3], ms[11], mj[11]);
    CAS(ms[4], mj[4], ms[8], mj[8]);  CAS(ms[5], mj[5], ms[9], mj[9]);
    CAS(ms[6], mj[6], ms[10], mj[10]); CAS(ms[7], mj[7], ms[11], mj[11]);
    CAS(ms[0], mj[0], ms[2], mj[2]);  CAS(ms[1], mj[1], ms[3], mj[3]);
    CAS(ms[4], mj[4], ms[6], mj[6]);  CAS(ms[5], mj[5], ms[7], mj[7]);
    CAS(ms[8], mj[8], ms[10], mj[10]); CAS(ms[9], mj[9], ms[11], mj[11]);
    CAS(ms[0], mj[0], ms[1], mj[1]);  CAS(ms[2], mj[2], ms[3], mj[3]);
    CAS(ms[4], mj[4], ms[5], mj[5]);  CAS(ms[6], mj[6], ms[7], mj[7]);
    CAS(ms[8], mj[8], ms[9], mj[9]);  CAS(ms[10], mj[10], ms[11], mj[11]);
#pragma unroll
    for (int j = 0; j < 12; ++j) { s12[j] = ms[j]; i12[j] = mj[j]; }
  }
  // i12[0..11]: approx top-12 indices, identical in every lane/wave.

  // exact fp32 partial dots; B fragments RETAINED for the output sum.
  const float4* Arow = (const float4*)&A[(size_t)n * 1024];
  const int fbase = wh * 128 + lane * 2;
  float4 a4[2];
  a4[0] = Arow[fbase];
  a4[1] = Arow[fbase + 1];
  float4 bk0[12], bk1[12];
#pragma unroll
  for (int j = 0; j < 12; ++j) {
    const float4* Brow = (const float4*)&B[(size_t)i12[j] * 1024];
    bk0[j] = Brow[fbase];
    bk1[j] = Brow[fbase + 1];
  }
  float part[13];
  part[12] = a4[0].x * a4[0].x + a4[0].y * a4[0].y + a4[0].z * a4[0].z +
             a4[0].w * a4[0].w + a4[1].x * a4[1].x + a4[1].y * a4[1].y +
             a4[1].z * a4[1].z + a4[1].w * a4[1].w;
#pragma unroll
  for (int j = 0; j < 12; ++j) {
    part[j] = a4[0].x * bk0[j].x + a4[0].y * bk0[j].y + a4[0].z * bk0[j].z +
              a4[0].w * bk0[j].w;
    part[j] += a4[1].x * bk1[j].x + a4[1].y * bk1[j].y + a4[1].z * bk1[j].z +
               a4[1].w * bk1[j].w;
  }
#pragma unroll
  for (int r = 0; r < 13; ++r) {
#pragma unroll
    for (int off = 32; off >= 1; off >>= 1) part[r] += __shfl_xor(part[r], off, 64);
  }
  if (lane == 0) {
#pragma unroll
    for (int r = 0; r < 13; ++r) comb[rloc][wh][r] = part[r];
  }
  __syncthreads();
  float tot[13];
#pragma unroll
  for (int r = 0; r < 13; ++r) tot[r] = comb[rloc][0][r] + comb[rloc][1][r];

  // scratch-free uniform redundant selection: top-8 by (d2, idx).
  // used[] -> bitmask; wsel[] writes -> predicated unrolled register moves.
  const float x2 = tot[12];
  float d2v[12];
  float wsel[12];
#pragma unroll
  for (int j = 0; j < 12; ++j) {
    d2v[j] = x2 + y2g[i12[j]] - 2.0f * tot[j];
    wsel[j] = 0.0f;
  }
  unsigned usedmask = 0;
  float wsum = 0.0f;
#pragma unroll
  for (int k = 0; k < 8; ++k) {
    float bd = SENTINEL;
    int bi = 0x7fffffff, bslot = 0;
#pragma unroll
    for (int j = 0; j < 12; ++j) {
      const bool avail = ((usedmask >> j) & 1u) == 0u;
      const float d2 = d2v[j];
      const bool better =
          avail && (d2 < bd || (d2 == bd && i12[j] < bi));
      bd = better ? d2 : bd;
      bi = better ? i12[j] : bi;
      bslot = better ? j : bslot;
    }
    usedmask |= (1u << bslot);
    const float d2c = fmaxf(bd, 1e-12f);
    const float wv = 1.0f / (sqrtf(d2c) + 0.1f);
#pragma unroll
    for (int j = 0; j < 12; ++j)
      wsel[j] = (bslot == j) ? wv : wsel[j];
    wsum += wv;
  }
  const float inv = 1.0f / wsum;

  float4 o0 = {0, 0, 0, 0}, o1 = {0, 0, 0, 0};
#pragma unroll
  for (int j = 0; j < 12; ++j) {
    const float wv = wsel[j];
    o0.x += wv * bk0[j].x; o0.y += wv * bk0[j].y;
    o0.z += wv * bk0[j].z; o0.w += wv * bk0[j].w;
    o1.x += wv * bk1[j].x; o1.y += wv * bk1[j].y;
    o1.z += wv * bk1[j].z; o1.w += wv * bk1[j].w;
  }
  o0.x *= inv; o0.y *= inv; o0.z *= inv; o0.w *= inv;
  o1.x *= inv; o1.y *= inv; o1.z *= inv; o1.w *= inv;
  float4* Orow = (float4*)&out[(size_t)n * 1024];
  Orow[fbase] = o0;
  Orow[fbase + 1] = o1;
}

// ---------------- fallback path (round-1, verified) ----------------
__global__ __launch_bounds__(256) void rownorm_kernel(
    const float* __restrict__ B, float* __restrict__ y2) {
  const int m = blockIdx.x;
  const int tid = threadIdx.x;
  __shared__ float red[256];
  const float4 v = *(const float4*)&B[(size_t)m * 1024 + tid * 4];
  red[tid] = v.x * v.x + v.y * v.y + v.z * v.z + v.w * v.w;
  __syncthreads();
  for (int s = 128; s > 0; s >>= 1) {
    if (tid < s) red[tid] += red[tid + s];
    __syncthreads();
  }
  if (tid == 0) y2[m] = red[0];
}

__global__ __launch_bounds__(256) void knn_chunk_kernel(
    const float* __restrict__ A, const float* __restrict__ B,
    const float* __restrict__ y2g,
    float* __restrict__ cand_s, int* __restrict__ cand_i) {
  __shared__ float As[BKK][68];
  __shared__ float Bs[BKK][68];
  __shared__ float Sc[64][65];

  const int tid = threadIdx.x;
  const int tx = tid & 15;
  const int ty = tid >> 4;
  const int r0 = blockIdx.y * 64;
  const int c0 = blockIdx.x * 1024;
  const int lrow = tid >> 3;
  const int lk = (tid & 7) * 4;

  float top_s[8];
  int top_i[8];
#pragma unroll
  for (int j = 0; j < 8; ++j) { top_s[j] = SENTINEL; top_i[j] = 0x7fffffff; }

  for (int tile = 0; tile < 16; ++tile) {
    const int cbase = c0 + tile * 64;
    float acc[4][4];
#pragma unroll
    for (int i = 0; i < 4; ++i)
#pragma unroll
      for (int j = 0; j < 4; ++j) acc[i][j] = 0.0f;

    for (int k0 = 0; k0 < 1024; k0 += BKK) {
      const float4 a0 = *(const float4*)&A[(size_t)(r0 + lrow) * 1024 + k0 + lk];
      const float4 a1 = *(const float4*)&A[(size_t)(r0 + lrow + 32) * 1024 + k0 + lk];
      const float4 b0 = *(const float4*)&B[(size_t)(cbase + lrow) * 1024 + k0 + lk];
      const float4 b1 = *(const float4*)&B[(size_t)(cbase + lrow + 32) * 1024 + k0 + lk];
      __syncthreads();
      As[lk + 0][lrow] = a0.x; As[lk + 1][lrow] = a0.y;
      As[lk + 2][lrow] = a0.z; As[lk + 3][lrow] = a0.w;
      As[lk + 0][lrow + 32] = a1.x; As[lk + 1][lrow + 32] = a1.y;
      As[lk + 2][lrow + 32] = a1.z; As[lk + 3][lrow + 32] = a1.w;
      Bs[lk + 0][lrow] = b0.x; Bs[lk + 1][lrow] = b0.y;
      Bs[lk + 2][lrow] = b0.z; Bs[lk + 3][lrow] = b0.w;
      Bs[lk + 0][lrow + 32] = b1.x; Bs[lk + 1][lrow + 32] = b1.y;
      Bs[lk + 2][lrow + 32] = b1.z; Bs[lk + 3][lrow + 32] = b1.w;
      __syncthreads();
#pragma unroll
      for (int kk = 0; kk < BKK; ++kk) {
        const float4 av = *(const float4*)&As[kk][ty * 4];
        const float4 bv = *(const float4*)&Bs[kk][tx * 4];
        acc[0][0] += av.x * bv.x; acc[0][1] += av.x * bv.y;
        acc[0][2] += av.x * bv.z; acc[0][3] += av.x * bv.w;
        acc[1][0] += av.y * bv.x; acc[1][1] += av.y * bv.y;
        acc[1][2] += av.y * bv.z; acc[1][3] += av.y * bv.w;
        acc[2][0] += av.z * bv.x; acc[2][1] += av.z * bv.y;
        acc[2][2] += av.z * bv.z; acc[2][3] += av.z * bv.w;
        acc[3][0] += av.w * bv.x; acc[3][1] += av.w * bv.y;
        acc[3][2] += av.w * bv.z; acc[3][3] += av.w * bv.w;
      }
    }
#pragma unroll
    for (int i = 0; i < 4; ++i) {
      const int row = ty * 4 + i;
#pragma unroll
      for (int j = 0; j < 4; ++j) {
        const int col = tx * 4 + j;
        Sc[row][col] = y2g[cbase + col] - 2.0f * acc[i][j];
      }
    }
    __syncthreads();
    if (tid < 64) {
      for (int c = 0; c < 64; ++c) {
        const float s = Sc[tid][c];
        if (s < top_s[7]) {
          top_s[7] = s; top_i[7] = cbase + c;
#pragma unroll
          for (int j = 7; j > 0; --j) {
            if (top_s[j] < top_s[j - 1]) {
              const float tss = top_s[j]; top_s[j] = top_s[j - 1]; top_s[j - 1] = tss;
              const int tii = top_i[j]; top_i[j] = top_i[j - 1]; top_i[j - 1] = tii;
            }
          }
        }
      }
    }
  }

  if (tid < 64) {
    const int n = r0 + tid;
    const int base = (n * gridDim.x + blockIdx.x) * 8;
#pragma unroll
    for (int j = 0; j < 8; ++j) {
      cand_s[base + j] = top_s[j];
      cand_i[base + j] = top_i[j];
    }
  }
}

__global__ __launch_bounds__(256) void finalize_kernel(
    const float* __restrict__ A, const float* __restrict__ B,
    const float* __restrict__ cand_s, const int* __restrict__ cand_i,
    float* __restrict__ out, int nchunks) {
  const int n = blockIdx.x;
  const int tid = threadIdx.x;
  __shared__ float red[256];
  __shared__ float ls[64];
  __shared__ int li[64];
  __shared__ float wsh2[8];
  __shared__ int wid[8];
  __shared__ float wsum_sh;

  const int ncand = nchunks * 8;
  const float4 a = *(const float4*)&A[(size_t)n * 1024 + tid * 4];
  red[tid] = a.x * a.x + a.y * a.y + a.z * a.z + a.w * a.w;
  if (tid < ncand) {
    ls[tid] = cand_s[n * ncand + tid];
    li[tid] = cand_i[n * ncand + tid];
  }
  __syncthreads();
  for (int s = 128; s > 0; s >>= 1) {
    if (tid < s) red[tid] += red[tid + s];
    __syncthreads();
  }
  if (tid == 0) {
    const float x2 = red[0];
    float wsum = 0.0f;
    for (int j = 0; j < 8; ++j) {
      float bs = SENTINEL;
      int bi = 0x7fffffff;
      int bp = 0;
      for (int c = 0; c < ncand; ++c) {
        const float s_ = ls[c];
        const int i_ = li[c];
        if (s_ < bs || (s_ == bs && i_ < bi)) { bs = s_; bi = i_; bp = c; }
      }
      ls[bp] = SENTINEL; li[bp] = 0x7fffffff;
      float d2 = x2 + bs;
      d2 = fmaxf(d2, 1e-12f);
      const float wkk = 1.0f / (sqrtf(d2) + 0.1f);
      wsh2[j] = wkk; wid[j] = bi;
      wsum += wkk;
    }
    wsum_sh = wsum;
  }
  __syncthreads();
  const float inv = 1.0f / wsum_sh;
  float ox = 0.0f, oy = 0.0f, oz = 0.0f, ow = 0.0f;
#pragma unroll
  for (int j = 0; j < 8; ++j) {
    const float wkk = wsh2[j];
    const float4 v = *(const float4*)&B[(size_t)wid[j] * 1024 + tid * 4];
    ox += wkk * v.x; oy += wkk * v.y; oz += wkk * v.z; ow += wkk * v.w;
  }
  float4 o;
  o.x = ox * inv; o.y = oy * inv; o.z = oz * inv; o.w = ow * inv;
  *(float4*)&out[(size_t)n * 1024 + tid * 4] = o;
}

extern "C" void kernel_launch(void* const* d_in, const int* in_sizes, int n_in,
                              void* d_out, int out_size, void* d_ws, size_t ws_size,
                              hipStream_t stream) {
  const float* A = (const float*)d_in[0];
  const float* Bm = (const float*)d_in[1];
  const int D = 1024;
  const int N = in_sizes[0] / D;  // 4096
  const int M = in_sizes[1] / D;  // 8192

  const size_t needA = (size_t)N * D * 2;
  const size_t needB = (size_t)M * D * 2;
  const size_t needC = (size_t)N * 512 * 4;  // cand_s (== cand_i)
  const size_t need = needA + needB + (size_t)M * 4 + 2 * needC;

  if (ws_size >= need && M == 8192 && N % 64 == 0 && N % 2 == 0) {
    unsigned short* Abf = (unsigned short*)d_ws;
    unsigned short* Bbf = Abf + (size_t)N * D;
    float* y2 = (float*)(Bbf + (size_t)M * D);
    float* cand_s = y2 + M;
    int* cand_i = (int*)(cand_s + (size_t)N * 512);

    convert_all_kernel<<<N + M, 256, 0, stream>>>(A, Bm, Abf, Bbf, y2, N);
    dim3 g(64, N / 64);
    screen14_kernel<<<g, 256, 0, stream>>>(Abf, Bbf, y2, cand_s, cand_i);
    finalize7_kernel<<<N / 2, 256, 0, stream>>>(A, Bm, y2, cand_s, cand_i,
                                                (float*)d_out);
  } else {
    float* y2 = (float*)d_ws;
    float* cand_s = y2 + M;
    int* cand_i = (int*)(cand_s + (size_t)N * 64);
    rownorm_kernel<<<M, 256, 0, stream>>>(Bm, y2);
    dim3 gridB(M / 1024, N / 64);
    knn_chunk_kernel<<<gridB, 256, 0, stream>>>(A, Bm, y2, cand_s, cand_i);
    finalize_kernel<<<N, 256, 0, stream>>>(A, Bm, cand_s, cand_i, (float*)d_out, M / 1024);
  }
}